// Round 3
// baseline (1459.593 us; speedup 1.0000x reference)
//
#include <hip/hip_runtime.h>
#include <math.h>

#define BB 8
#define PP 64
#define LL 32
#define LMAXX 2048
#define INDIM 12
#define PNT 32
#define HIDD 128
#define TTCNN 127
#define NPATCH 512

#define EPI_NONE 0
#define EPI_RELU 1
#define EPI_GA   2
#define EPI_LN   3
#define EPI_LNF  4

// ---------------------------------------------------------------- tables
__global__ void tables_kernel(float* __restrict__ tb, float* __restrict__ pe)
{
    int e = blockIdx.x*256 + threadIdx.x;
    if (e < 64*64) {
        int i = e >> 6, j = e & 63;
        float dist = fabsf((float)(i - j)) * (300.0f / 300.0f); // DELTA/TAU
        tb[e] = logf(expf(-dist) + 1e-12f);
    } else if (e < 64*64 + 64*128) {
        int e2 = e - 64*64;
        int i = e2 >> 7, d = e2 & 127;
        int mm = d >> 1;
        float div = expf((float)(2*mm) * (-logf(10000.f)/128.f));
        float ang = (float)i * div;
        pe[e2] = (d & 1) ? cosf(ang) : sinf(ang);
    }
}

// ---------------------------------------------------------------- W3 transpose (pad K to 128 with zeros)
__global__ void w3t_kernel(const float* __restrict__ W3, float* __restrict__ W3T)
{
    int e = blockIdx.x*256 + threadIdx.x;   // 4064*128 total
    if (e >= 4064*128) return;
    int cidx = e % 4064, kk = e / 4064;
    W3T[cidx*128 + kk] = (kk < TTCNN) ? W3[kk*4064 + cidx] : 0.f;
}

// ---------------------------------------------------------------- gather + time-encode -> X_int, mask
__global__ void prep_kernel(const float* __restrict__ data, const float* __restrict__ ts,
                            const float* __restrict__ pmask, const int* __restrict__ pindex,
                            const int* __restrict__ nbatch,
                            const float* __restrict__ teW, const float* __restrict__ teB,
                            const float* __restrict__ tePW, const float* __restrict__ tePB,
                            float* __restrict__ xint, float* __restrict__ maskout)
{
    int n = blockIdx.x;
    int b = n >> 6, p = n & 63;
    __shared__ int s_start, s_len;
    __shared__ float s_mk[LL];
    if (threadIdx.x == 0) {
        int start = 0;
        for (int j = 0; j < p; ++j) {
            float mv = pmask[b*PP + j];
            int pi = pindex[b*PP + j];
            start += (mv > 0.f) ? (pi > 0 ? pi : 0) : 0;
        }
        float mvp = pmask[b*PP + p];
        int pip = pindex[b*PP + p];
        s_len = (mvp > 0.f) ? (pip > 0 ? pip : 0) : 0;
        s_start = start;
    }
    __syncthreads();
    int start = s_start, len = s_len, nb = nbatch[b];
    if (threadIdx.x < LL) {
        int l = threadIdx.x;
        int idx = start + l;
        float v = (l < len && idx < nb) ? 1.f : 0.f;
        s_mk[l] = v;
        maskout[n*LL + l] = v;
    }
    __syncthreads();
    for (int e = threadIdx.x; e < LL*PNT; e += blockDim.x) {
        int l = e >> 5, d = e & 31;
        float mv = s_mk[l];
        int idx = start + l;
        if (idx < 0) idx = 0;
        if (idx > LMAXX-1) idx = LMAXX-1;
        float val;
        if (d < INDIM) {
            val = (mv > 0.f) ? data[(b*LMAXX + idx)*INDIM + d] : 0.f;
        } else {
            float tsm = (mv > 0.f) ? ts[b*LMAXX + idx] : 0.f;
            if (d == INDIM) val = tsm * teW[0] + teB[0];
            else { int j = d - INDIM - 1; val = sinf(tsm * tePW[j] + tePB[j]); }
        }
        xint[n*(LL*PNT) + e] = val;
    }
}

// ---------------------------------------------------------------- filter-gen MLP first two layers -> h2
__global__ void h2_kernel(const float* __restrict__ xint,
                          const float* __restrict__ W1, const float* __restrict__ b1,
                          const float* __restrict__ W2, const float* __restrict__ b2,
                          float* __restrict__ h2o)
{
    int n = blockIdx.x;
    __shared__ alignas(16) float Xs[LL*36];
    __shared__ alignas(16) float H1[LL*128];
    int tid = threadIdx.x;
    for (int f = tid; f < LL*8; f += blockDim.x) {
        int l = f >> 3, d4 = (f & 7)*4;
        *(float4*)&Xs[l*36 + d4] = *(const float4*)&xint[n*1024 + l*32 + d4];
    }
    __syncthreads();
    int j = tid;  // 0..127
    float acc[LL];
    if (j < TTCNN) {
        #pragma unroll
        for (int l = 0; l < LL; ++l) acc[l] = b1[j];
        for (int d4 = 0; d4 < 8; ++d4) {
            float w0 = W1[(d4*4+0)*TTCNN + j];
            float w1 = W1[(d4*4+1)*TTCNN + j];
            float w2 = W1[(d4*4+2)*TTCNN + j];
            float w3 = W1[(d4*4+3)*TTCNN + j];
            #pragma unroll
            for (int l = 0; l < LL; ++l) {
                float4 x = *(float4*)&Xs[l*36 + d4*4];
                acc[l] = fmaf(x.x, w0, acc[l]);
                acc[l] = fmaf(x.y, w1, acc[l]);
                acc[l] = fmaf(x.z, w2, acc[l]);
                acc[l] = fmaf(x.w, w3, acc[l]);
            }
        }
        #pragma unroll
        for (int l = 0; l < LL; ++l) H1[l*128 + j] = fmaxf(acc[l], 0.f);
    } else {
        #pragma unroll
        for (int l = 0; l < LL; ++l) H1[l*128 + 127] = 0.f;
    }
    __syncthreads();
    if (j < TTCNN) {
        #pragma unroll
        for (int l = 0; l < LL; ++l) acc[l] = b2[j];
        for (int k4 = 0; k4 < 32; ++k4) {
            int k = k4*4;
            float w0 = W2[(k+0)*TTCNN + j];
            float w1 = W2[(k+1)*TTCNN + j];
            float w2 = W2[(k+2)*TTCNN + j];
            float w3 = (k+3 < TTCNN) ? W2[(k+3)*TTCNN + j] : 0.f;
            #pragma unroll
            for (int l = 0; l < LL; ++l) {
                float4 h = *(float4*)&H1[l*128 + k];
                acc[l] = fmaf(h.x, w0, acc[l]);
                acc[l] = fmaf(h.y, w1, acc[l]);
                acc[l] = fmaf(h.z, w2, acc[l]);
                acc[l] = fmaf(h.w, w3, acc[l]);
            }
        }
        #pragma unroll
        for (int l = 0; l < LL; ++l) h2o[(n*LL + l)*128 + j] = fmaxf(acc[l], 0.f);
    } else {
        #pragma unroll
        for (int l = 0; l < LL; ++l) h2o[(n*LL + l)*128 + 127] = 0.f;
    }
}

// ---------------------------------------------------------------- fused Filt GEMM + softmax + TTCN contraction
__global__ __launch_bounds__(256, 2) void ttcn_kernel(
    const float* __restrict__ h2i, const float* __restrict__ xint,
    const float* __restrict__ mask, const float* __restrict__ w3t,
    const float* __restrict__ b3, const float* __restrict__ tbias,
    float* __restrict__ x)
{
    int n = blockIdx.x;
    __shared__ alignas(16) float H[LL*132];
    __shared__ alignas(16) float Xs[LL*36];
    __shared__ alignas(16) float Fb[4*LL*36];
    __shared__ float mk[LL];
    int tid = threadIdx.x;
    for (int f = tid; f < LL*32; f += 256) {
        int l = f >> 5, k4 = (f & 31)*4;
        *(float4*)&H[l*132 + k4] = *(const float4*)&h2i[(n*LL + l)*128 + k4];
    }
    for (int f = tid; f < LL*8; f += 256) {
        int l = f >> 3, d4 = (f & 7)*4;
        *(float4*)&Xs[l*36 + d4] = *(const float4*)&xint[n*1024 + l*32 + d4];
    }
    if (tid < LL) mk[tid] = mask[n*LL + tid];
    __syncthreads();
    if (tid == 0) {
        float e = 0.f;
        for (int l = 0; l < LL; ++l) e += mk[l];
        x[n*HIDD + 127] = (e > 0.f) ? 1.f : 0.f;
    }
    int sub = tid >> 6, lane = tid & 63;
    int lg = lane >> 3, pg = lane & 7;
    for (int qi = 0; qi < 32; ++qi) {
        int t = qi*4 + sub;
        int trow = (t < TTCNN) ? t : 0;
        float acc[4][4];
        #pragma unroll
        for (int i = 0; i < 4; ++i)
            #pragma unroll
            for (int jj = 0; jj < 4; ++jj) acc[i][jj] = 0.f;
        const float* wbase = w3t + (trow*32 + pg)*128;
        for (int kc = 0; kc < 32; ++kc) {
            int k = kc*4;
            float4 h0 = *(float4*)&H[(lg     )*132 + k];
            float4 h1 = *(float4*)&H[(lg +  8)*132 + k];
            float4 h2v= *(float4*)&H[(lg + 16)*132 + k];
            float4 h3 = *(float4*)&H[(lg + 24)*132 + k];
            #pragma unroll
            for (int jj = 0; jj < 4; ++jj) {
                float4 w = *(const float4*)&wbase[jj*8*128 + k];
                acc[0][jj] += h0.x*w.x + h0.y*w.y + h0.z*w.z + h0.w*w.w;
                acc[1][jj] += h1.x*w.x + h1.y*w.y + h1.z*w.z + h1.w*w.w;
                acc[2][jj] += h2v.x*w.x + h2v.y*w.y + h2v.z*w.z + h2v.w*w.w;
                acc[3][jj] += h3.x*w.x + h3.y*w.y + h3.z*w.z + h3.w*w.w;
            }
        }
        #pragma unroll
        for (int jj = 0; jj < 4; ++jj) {
            float bv = b3[trow*32 + jj*8 + pg];
            #pragma unroll
            for (int i = 0; i < 4; ++i)
                Fb[sub*(LL*36) + (i*8 + lg)*36 + jj*8 + pg] = acc[i][jj] + bv;
        }
        __syncthreads();
        if (tid < 128) {
            int sub2 = tid >> 5, p = tid & 31;
            int t2 = qi*4 + sub2;
            if (t2 < TTCNN) {
                const float* fb = &Fb[sub2*(LL*36) + p];
                float m = -3.0e38f;
                #pragma unroll 8
                for (int l = 0; l < LL; ++l) {
                    float mv = mk[l];
                    float fm = fb[l*36]*mv + (1.f - mv)*(-1e8f);
                    m = fmaxf(m, fm);
                }
                float s = 0.f, wsum = 0.f;
                #pragma unroll 8
                for (int l = 0; l < LL; ++l) {
                    float mv = mk[l];
                    float fm = fb[l*36]*mv + (1.f - mv)*(-1e8f);
                    float e = expf(fm - m);
                    s += e;
                    wsum += Xs[l*36 + p]*e;
                }
                float colv = wsum / s;
                colv += __shfl_xor(colv, 16);
                colv += __shfl_xor(colv, 8);
                colv += __shfl_xor(colv, 4);
                colv += __shfl_xor(colv, 2);
                colv += __shfl_xor(colv, 1);
                if (p == 0) {
                    float tt = colv + tbias[t2];
                    x[n*HIDD + t2] = fmaxf(tt, 0.f);
                }
            }
        }
        __syncthreads();
    }
}

// ---------------------------------------------------------------- generic fused linear (N multiple of 128)
__global__ __launch_bounds__(256) void lin_kernel(
    const float* __restrict__ A, int lda,
    const float* __restrict__ W0, const float* __restrict__ Wb0,
    const float* __restrict__ W1, const float* __restrict__ Wb1,
    const float* __restrict__ W2, const float* __restrict__ Wb2,
    float* __restrict__ O0, float* __restrict__ O1, float* __restrict__ O2,
    int M, int K, int N, int epi,
    const float* __restrict__ xres, const float* __restrict__ xlast_in,
    float* __restrict__ xlast_out,
    const float* __restrict__ pmk, const float* __restrict__ pe,
    const float* __restrict__ g, const float* __restrict__ bt)
{
    __shared__ alignas(16) float As[8*68];
    __shared__ float red[4][4][2];
    int tid = threadIdx.x;
    int cloc = tid & 127, rh = tid >> 7;
    int c = blockIdx.z*128 + cloc;
    int r0 = blockIdx.x*8;
    const float* W; const float* Wb; float* O;
    if (blockIdx.y == 0)      { W = W0; Wb = Wb0; O = O0; }
    else if (blockIdx.y == 1) { W = W1; Wb = Wb1; O = O1; }
    else                      { W = W2; Wb = Wb2; O = O2; }
    float acc0 = 0.f, acc1 = 0.f, acc2 = 0.f, acc3 = 0.f;
    for (int kc = 0; kc < K; kc += 64) {
        __syncthreads();
        if (tid < 128) {
            int row = tid >> 4, kk = (tid & 15)*4;
            int r = r0 + row;
            float4 v = make_float4(0.f, 0.f, 0.f, 0.f);
            if (r < M) v = *(const float4*)&A[(size_t)r*lda + kc + kk];
            *(float4*)&As[row*68 + kk] = v;
        }
        __syncthreads();
        const float* wp = &W[(size_t)kc*N + c];
        #pragma unroll 4
        for (int kk4 = 0; kk4 < 16; ++kk4) {
            float w0 = wp[(size_t)(kk4*4+0)*N];
            float w1 = wp[(size_t)(kk4*4+1)*N];
            float w2 = wp[(size_t)(kk4*4+2)*N];
            float w3 = wp[(size_t)(kk4*4+3)*N];
            float4 a0 = *(float4*)&As[(rh*4+0)*68 + kk4*4];
            float4 a1 = *(float4*)&As[(rh*4+1)*68 + kk4*4];
            float4 a2 = *(float4*)&As[(rh*4+2)*68 + kk4*4];
            float4 a3 = *(float4*)&As[(rh*4+3)*68 + kk4*4];
            acc0 += a0.x*w0 + a0.y*w1 + a0.z*w2 + a0.w*w3;
            acc1 += a1.x*w0 + a1.y*w1 + a1.z*w2 + a1.w*w3;
            acc2 += a2.x*w0 + a2.y*w1 + a2.z*w2 + a2.w*w3;
            acc3 += a3.x*w0 + a3.y*w1 + a3.z*w2 + a3.w*w3;
        }
    }
    float bv = Wb ? Wb[c] : 0.f;
    float val[4] = {acc0 + bv, acc1 + bv, acc2 + bv, acc3 + bv};
    int rbase = r0 + rh*4;
    if (epi == EPI_NONE || epi == EPI_RELU) {
        #pragma unroll
        for (int i = 0; i < 4; ++i) {
            int r = rbase + i;
            if (r < M) {
                float v = val[i];
                if (epi == EPI_RELU) v = fmaxf(v, 0.f);
                O[(size_t)r*N + c] = v;
            }
        }
    } else if (epi == EPI_GA) {
        #pragma unroll
        for (int i = 0; i < 4; ++i) {
            int r = rbase + i;
            float xr = xres[r*128 + cloc];
            float pmv = pmk[r];
            float pev = pe[(r & 63)*128 + cloc];
            xlast_out[r*128 + cloc] = xr;
            O[r*128 + cloc] = xr + val[i]*pmv + pev;
        }
    } else {
        float tv[4], s[4], s2[4];
        #pragma unroll
        for (int i = 0; i < 4; ++i) {
            int r = rbase + i;
            tv[i] = xres[r*128 + cloc] + val[i];
            s[i] = tv[i];
            s2[i] = tv[i]*tv[i];
        }
        #pragma unroll
        for (int i = 0; i < 4; ++i) {
            for (int off = 32; off >= 1; off >>= 1) {
                s[i]  += __shfl_xor(s[i],  off);
                s2[i] += __shfl_xor(s2[i], off);
            }
        }
        int wid = tid >> 6;
        if ((tid & 63) == 0) {
            #pragma unroll
            for (int i = 0; i < 4; ++i) { red[wid][i][0] = s[i]; red[wid][i][1] = s2[i]; }
        }
        __syncthreads();
        int pw = wid ^ 1;
        #pragma unroll
        for (int i = 0; i < 4; ++i) {
            float st  = red[wid][i][0] + red[pw][i][0];
            float s2t = red[wid][i][1] + red[pw][i][1];
            float mean = st * (1.f/128.f);
            float var = s2t * (1.f/128.f) - mean*mean;
            float rs = rsqrtf(var + 1e-5f);
            float y = (tv[i] - mean)*rs*g[cloc] + bt[cloc];
            int r = rbase + i;
            if (epi == EPI_LN) O[r*128 + cloc] = y;
            else               O[r*128 + cloc] = (xlast_in[r*128 + cloc] + y)*pmk[r];
        }
    }
}

// ---------------------------------------------------------------- 64-token MHA (4 heads, dh=32)
__global__ __launch_bounds__(256) void attn_kernel(
    const float* __restrict__ q, const float* __restrict__ k, const float* __restrict__ v,
    float* __restrict__ out, const float* __restrict__ tb,
    const float* __restrict__ pmk, int flags)
{
    int b = blockIdx.x >> 2, h = blockIdx.x & 3;
    __shared__ alignas(16) float qs[64*36];
    __shared__ alignas(16) float ks[64*36];
    __shared__ alignas(16) float vs[64*36];
    __shared__ float as_[64*68];
    int tid = threadIdx.x;
    for (int f = tid; f < 512; f += 256) {
        int m = f >> 3, d4 = (f & 7)*4;
        int gofs = (b*64 + m)*128 + h*32 + d4;
        *(float4*)&qs[m*36 + d4] = *(const float4*)&q[gofs];
        *(float4*)&ks[m*36 + d4] = *(const float4*)&k[gofs];
        *(float4*)&vs[m*36 + d4] = *(const float4*)&v[gofs];
    }
    __syncthreads();
    int r = tid >> 2, qd = tid & 3;
    float sreg[16];
    #pragma unroll
    for (int j = 0; j < 16; ++j) {
        int cc = qd*16 + j;
        float acc = 0.f;
        #pragma unroll
        for (int d4 = 0; d4 < 8; ++d4) {
            float4 a = *(float4*)&qs[r*36 + d4*4];
            float4 bb = *(float4*)&ks[cc*36 + d4*4];
            acc += a.x*bb.x + a.y*bb.y + a.z*bb.z + a.w*bb.w;
        }
        float s = acc * 0.17677669529663687f;
        if (flags & 1) s += tb[r*64 + cc];
        if (flags & 2) { if (pmk[b*64 + cc] <= 0.f) s = -1e9f; }
        sreg[j] = s;
    }
    float m = sreg[0];
    #pragma unroll
    for (int j = 1; j < 16; ++j) m = fmaxf(m, sreg[j]);
    m = fmaxf(m, __shfl_xor(m, 1));
    m = fmaxf(m, __shfl_xor(m, 2));
    float ssum = 0.f;
    #pragma unroll
    for (int j = 0; j < 16; ++j) { sreg[j] = expf(sreg[j] - m); ssum += sreg[j]; }
    ssum += __shfl_xor(ssum, 1);
    ssum += __shfl_xor(ssum, 2);
    float inv = 1.f / ssum;
    #pragma unroll
    for (int j = 0; j < 16; ++j) as_[r*68 + qd*16 + j] = sreg[j]*inv;
    __syncthreads();
    float o[8] = {0,0,0,0,0,0,0,0};
    for (int cc = 0; cc < 64; ++cc) {
        float a = as_[r*68 + cc];
        float4 v0 = *(float4*)&vs[cc*36 + qd*8];
        float4 v1 = *(float4*)&vs[cc*36 + qd*8 + 4];
        o[0] += a*v0.x; o[1] += a*v0.y; o[2] += a*v0.z; o[3] += a*v0.w;
        o[4] += a*v1.x; o[5] += a*v1.y; o[6] += a*v1.z; o[7] += a*v1.w;
    }
    int gobase = (b*64 + r)*128 + h*32 + qd*8;
    *(float4*)&out[gobase]   = make_float4(o[0], o[1], o[2], o[3]);
    *(float4*)&out[gobase+4] = make_float4(o[4], o[5], o[6], o[7]);
}

// ---------------------------------------------------------------- Weff = cls_Wo @ cls_out_W ; beff
__global__ void weff_kernel(const float* __restrict__ Wo, const float* __restrict__ bo,
                            const float* __restrict__ Wout, const float* __restrict__ bout,
                            float* __restrict__ weff)
{
    int d = threadIdx.x;
    float s = 0.f;
    for (int cc = 0; cc < 128; ++cc) s += Wo[d*128 + cc]*Wout[cc];
    weff[d] = s;
    if (d == 0) {
        float t = bout[0];
        for (int cc = 0; cc < 128; ++cc) t += bo[cc]*Wout[cc];
        weff[128] = t;
    }
}

// ---------------------------------------------------------------- cls attention + final logits
__global__ __launch_bounds__(256) void cls_attn_kernel(
    const float* __restrict__ qc, const float* __restrict__ k, const float* __restrict__ v,
    const float* __restrict__ pmk, const float* __restrict__ weff,
    float* __restrict__ outp)
{
    int b = blockIdx.x;
    __shared__ alignas(16) float ks[64*132];
    __shared__ alignas(16) float vs[64*132];
    __shared__ alignas(16) float q5[5*132];
    __shared__ float sb[5*68];
    __shared__ float z[5*132];
    int tid = threadIdx.x;
    for (int f = tid; f < 64*32; f += 256) {
        int m = f >> 5, d4 = (f & 31)*4;
        *(float4*)&ks[m*132 + d4] = *(const float4*)&k[(b*64+m)*128 + d4];
        *(float4*)&vs[m*132 + d4] = *(const float4*)&v[(b*64+m)*128 + d4];
    }
    for (int e = tid; e < 5*128; e += 256) {
        q5[(e >> 7)*132 + (e & 127)] = qc[e];
        z[(e >> 7)*132 + (e & 127)] = 0.f;
    }
    __syncthreads();
    for (int h = 0; h < 4; ++h) {
        for (int it = tid; it < 5*64; it += 256) {
            int qr = it >> 6, cc = it & 63;
            float acc = 0.f;
            #pragma unroll
            for (int d4 = 0; d4 < 8; ++d4) {
                float4 a = *(float4*)&q5[qr*132 + h*32 + d4*4];
                float4 bb = *(float4*)&ks[cc*132 + h*32 + d4*4];
                acc += a.x*bb.x + a.y*bb.y + a.z*bb.z + a.w*bb.w;
            }
            float s = acc * 0.17677669529663687f;
            if (pmk[b*64 + cc] <= 0.f) s = -1e9f;
            sb[qr*68 + cc] = s;
        }
        __syncthreads();
        if (tid < 5) {
            float m = -3e38f;
            for (int cc = 0; cc < 64; ++cc) m = fmaxf(m, sb[tid*68 + cc]);
            float ssum = 0.f;
            for (int cc = 0; cc < 64; ++cc) {
                float e = expf(sb[tid*68 + cc] - m);
                sb[tid*68 + cc] = e;
                ssum += e;
            }
            float inv = 1.f/ssum;
            for (int cc = 0; cc < 64; ++cc) sb[tid*68 + cc] *= inv;
        }
        __syncthreads();
        for (int it = tid; it < 5*32; it += 256) {
            int qr = it >> 5, d = it & 31;
            float acc = 0.f;
            for (int cc = 0; cc < 64; ++cc) acc += sb[qr*68 + cc]*vs[cc*132 + h*32 + d];
            z[qr*132 + h*32 + d] = acc;
        }
        __syncthreads();
    }
    if (tid < 5) {
        float acc = weff[128];
        for (int d = 0; d < 128; ++d) acc += z[tid*132 + d]*weff[d];
        outp[b*5 + tid] = acc;
    }
}

// ================================================================ launch
extern "C" void kernel_launch(void* const* d_in, const int* in_sizes, int n_in,
                              void* d_out, int out_size, void* d_ws, size_t ws_size,
                              hipStream_t stream)
{
    (void)n_in; (void)out_size; (void)ws_size;
    #define FP(i) ((const float*)d_in[i])
    const float* data = FP(0);
    const float* ts   = FP(1);
    const float* pmask= FP(2);
    const int*   pidx = (const int*)d_in[3];
    const int*   nb   = (const int*)d_in[4];
    const float* teW  = FP(5);
    const float* teB  = FP(6);
    const float* tePW = FP(7);
    const float* tePB = FP(8);
    const float* fgW1 = FP(9);
    const float* fgb1 = FP(10);
    const float* fgW2 = FP(11);
    const float* fgb2 = FP(12);
    const float* fgW3 = FP(13);
    const float* fgb3 = FP(14);
    const float* Tb   = FP(15);
    const float *gaWq,*gaWk,*gaWv,*gaWo,*tfWq,*tfWk,*tfWv,*tfWo;
    const float *gabq,*gabk,*gabv,*gabo,*tfbq,*tfbk,*tfbv,*tfbo,*ffb2;
    const float *ln1g,*ln1b,*ln2g,*ln2b,*ffW1,*ffb1,*ffW2;
    const float *clsq,*clsWq,*clsWk,*clsWv,*clsWo,*clsbq,*clsbk,*clsbv,*clsbo,*cloW,*clob;
    if (in_sizes[17] == 2*128*128) {  // setup_inputs dict order
        gaWq=FP(16); gaWk=FP(17); gaWv=FP(18); gaWo=FP(19);
        tfWq=FP(20); tfWk=FP(21); tfWv=FP(22); tfWo=FP(23);
        gabq=FP(24); gabk=FP(25); gabv=FP(26); gabo=FP(27);
        tfbq=FP(28); tfbk=FP(29); tfbv=FP(30); tfbo=FP(31);
        ffb2=FP(32); ln1g=FP(33); ln1b=FP(34); ln2g=FP(35); ln2b=FP(36);
        ffW1=FP(37); ffb1=FP(38); ffW2=FP(39);
        clsq=FP(40); clsWq=FP(41); clsWk=FP(42); clsWv=FP(43); clsWo=FP(44);
        clsbq=FP(45); clsbk=FP(46); clsbv=FP(47); clsbo=FP(48); cloW=FP(49); clob=FP(50);
    } else {                          // reference() signature order
        gaWq=FP(16); gabq=FP(17); gaWk=FP(18); gabk=FP(19);
        gaWv=FP(20); gabv=FP(21); gaWo=FP(22); gabo=FP(23);
        tfWq=FP(24); tfbq=FP(25); tfWk=FP(26); tfbk=FP(27);
        tfWv=FP(28); tfbv=FP(29); tfWo=FP(30); tfbo=FP(31);
        ln1g=FP(32); ln1b=FP(33); ffW1=FP(34); ffb1=FP(35); ffW2=FP(36); ffb2=FP(37);
        ln2g=FP(38); ln2b=FP(39);
        clsq=FP(40); clsWq=FP(41); clsbq=FP(42); clsWk=FP(43); clsbk=FP(44);
        clsWv=FP(45); clsbv=FP(46); clsWo=FP(47); clsbo=FP(48); cloW=FP(49); clob=FP(50);
    }

    float* ws   = (float*)d_ws;
    float* XINT = ws;                     // 524288
    float* MASK = ws + 524288;            // 16384
    float* W3T  = ws + 540672;            // 520192
    float* H2B  = ws + 1060864;           // 2097152
    float* X    = ws + 3158016;           // 65536
    float* XLAST= X + 65536;
    float* Q    = XLAST + 65536;
    float* Kb   = Q + 65536;
    float* Vb   = Kb + 65536;
    float* ATT  = Vb + 65536;
    float* HIDB = ATT + 65536;            // 1048576
    float* TBT  = HIDB + 1048576;         // 4096
    float* PET  = TBT + 4096;             // 8192
    float* WEFF = PET + 8192;             // 256
    float* QC5  = WEFF + 256;             // 640

    tables_kernel<<<48, 256, 0, stream>>>(TBT, PET);
    w3t_kernel<<<2032, 256, 0, stream>>>(fgW3, W3T);
    prep_kernel<<<512, 128, 0, stream>>>(data, ts, pmask, pidx, nb, teW, teB, tePW, tePB, XINT, MASK);
    h2_kernel<<<512, 128, 0, stream>>>(XINT, fgW1, fgb1, fgW2, fgb2, H2B);
    ttcn_kernel<<<512, 256, 0, stream>>>(H2B, XINT, MASK, W3T, fgb3, Tb, X);

    for (int l = 0; l < 2; ++l) {
        const float* Wq = gaWq + l*16384; const float* bq = gabq + l*128;
        const float* Wk = gaWk + l*16384; const float* bk = gabk + l*128;
        const float* Wv = gaWv + l*16384; const float* bv = gabv + l*128;
        const float* Wo = gaWo + l*16384; const float* bo = gabo + l*128;
        // ga qkv
        lin_kernel<<<dim3(64,3,1), 256, 0, stream>>>(X, 128, Wq,bq, Wk,bk, Wv,bv, Q,Kb,Vb,
            512,128,128, EPI_NONE, nullptr,nullptr,nullptr,nullptr,nullptr,nullptr,nullptr);
        attn_kernel<<<32, 256, 0, stream>>>(Q, Kb, Vb, ATT, TBT, pmask, 3);
        // ga out-proj: x = x + ga*pm + pe ; save x_last
        lin_kernel<<<dim3(64,1,1), 256, 0, stream>>>(ATT, 128, Wo,bo, Wo,bo, Wo,bo, X,X,X,
            512,128,128, EPI_GA, X, nullptr, XLAST, pmask, PET, nullptr, nullptr);
        // tf qkv
        const float* Wq2 = tfWq + l*16384; const float* bq2 = tfbq + l*128;
        const float* Wk2 = tfWk + l*16384; const float* bk2 = tfbk + l*128;
        const float* Wv2 = tfWv + l*16384; const float* bv2 = tfbv + l*128;
        const float* Wo2 = tfWo + l*16384; const float* bo2 = tfbo + l*128;
        lin_kernel<<<dim3(64,3,1), 256, 0, stream>>>(X, 128, Wq2,bq2, Wk2,bk2, Wv2,bv2, Q,Kb,Vb,
            512,128,128, EPI_NONE, nullptr,nullptr,nullptr,nullptr,nullptr,nullptr,nullptr);
        attn_kernel<<<32, 256, 0, stream>>>(Q, Kb, Vb, ATT, TBT, pmask, 0);
        // tf out-proj + LN1(x + a)
        lin_kernel<<<dim3(64,1,1), 256, 0, stream>>>(ATT, 128, Wo2,bo2, Wo2,bo2, Wo2,bo2, X,X,X,
            512,128,128, EPI_LN, X, nullptr, nullptr, nullptr, nullptr, ln1g + l*128, ln1b + l*128);
        // FF1 relu
        lin_kernel<<<dim3(64,1,16), 256, 0, stream>>>(X, 128,
            ffW1 + (size_t)l*128*2048, ffb1 + l*2048, ffW1, ffb1, ffW1, ffb1, HIDB,HIDB,HIDB,
            512,128,2048, EPI_RELU, nullptr,nullptr,nullptr,nullptr,nullptr,nullptr,nullptr);
        // FF2 + LN2(x+f) + final residual*pm
        lin_kernel<<<dim3(64,1,1), 256, 0, stream>>>(HIDB, 2048,
            ffW2 + (size_t)l*2048*128, ffb2 + l*128, ffW2, ffb2, ffW2, ffb2, X,X,X,
            512,2048,128, EPI_LNF, X, XLAST, nullptr, pmask, nullptr, ln2g + l*128, ln2b + l*128);
    }

    // cls head
    lin_kernel<<<dim3(1,1,1), 256, 0, stream>>>(clsq, 128, clsWq,clsbq, clsWq,clsbq, clsWq,clsbq,
        QC5,QC5,QC5, 5,128,128, EPI_NONE, nullptr,nullptr,nullptr,nullptr,nullptr,nullptr,nullptr);
    lin_kernel<<<dim3(64,2,1), 256, 0, stream>>>(X, 128, clsWk,clsbk, clsWv,clsbv, clsWv,clsbv,
        Kb,Vb,Vb, 512,128,128, EPI_NONE, nullptr,nullptr,nullptr,nullptr,nullptr,nullptr,nullptr);
    weff_kernel<<<1, 128, 0, stream>>>(clsWo, clsbo, cloW, clob, WEFF);
    cls_attn_kernel<<<8, 256, 0, stream>>>(QC5, Kb, Vb, pmask, WEFF, (float*)d_out);
}

// Round 4
// 595.968 us; speedup vs baseline: 2.4491x; 2.4491x over previous
//
#include <hip/hip_runtime.h>
#include <math.h>

#define BB 8
#define PP 64
#define LL 32
#define LMAXX 2048
#define INDIM 12
#define PNT 32
#define HIDD 128
#define TTCNN 127
#define NPATCH 512

#define EPI_NONE 0
#define EPI_RELU 1
#define EPI_GA   2
#define EPI_LN   3
#define EPI_LNF  4

typedef __attribute__((ext_vector_type(8))) short short8v;
typedef __attribute__((ext_vector_type(4))) float float4v;

__device__ inline unsigned short f2bf(float f) {
    unsigned int u = __float_as_uint(f);
    unsigned int r = (u + 0x7FFFu + ((u >> 16) & 1u)) >> 16;
    return (unsigned short)r;
}

// ---------------------------------------------------------------- tables
__global__ void tables_kernel(float* __restrict__ tb, float* __restrict__ pe)
{
    int e = blockIdx.x*256 + threadIdx.x;
    if (e < 64*64) {
        int i = e >> 6, j = e & 63;
        float dist = fabsf((float)(i - j)) * (300.0f / 300.0f); // DELTA/TAU
        tb[e] = logf(expf(-dist) + 1e-12f);
    } else if (e < 64*64 + 64*128) {
        int e2 = e - 64*64;
        int i = e2 >> 7, d = e2 & 127;
        int mm = d >> 1;
        float div = expf((float)(2*mm) * (-logf(10000.f)/128.f));
        float ang = (float)i * div;
        pe[e2] = (d & 1) ? cosf(ang) : sinf(ang);
    }
}

// ---------------------------------------------------------------- W3 transpose -> bf16 [4096 cols][128 k], zero-padded
__global__ void w3t_kernel(const float* __restrict__ W3, unsigned short* __restrict__ W3TB)
{
    int e = blockIdx.x*256 + threadIdx.x;   // 4096*128 total
    if (e >= 4096*128) return;
    int kk = e >> 12, cidx = e & 4095;
    float v = (kk < TTCNN && cidx < 4064) ? W3[kk*4064 + cidx] : 0.f;
    W3TB[cidx*128 + kk] = f2bf(v);
}

// ---------------------------------------------------------------- gather + time-encode -> X_int, mask
__global__ void prep_kernel(const float* __restrict__ data, const float* __restrict__ ts,
                            const float* __restrict__ pmask, const int* __restrict__ pindex,
                            const int* __restrict__ nbatch,
                            const float* __restrict__ teW, const float* __restrict__ teB,
                            const float* __restrict__ tePW, const float* __restrict__ tePB,
                            float* __restrict__ xint, float* __restrict__ maskout)
{
    int n = blockIdx.x;
    int b = n >> 6, p = n & 63;
    __shared__ int s_start, s_len;
    __shared__ float s_mk[LL];
    if (threadIdx.x == 0) {
        int start = 0;
        for (int j = 0; j < p; ++j) {
            float mv = pmask[b*PP + j];
            int pi = pindex[b*PP + j];
            start += (mv > 0.f) ? (pi > 0 ? pi : 0) : 0;
        }
        float mvp = pmask[b*PP + p];
        int pip = pindex[b*PP + p];
        s_len = (mvp > 0.f) ? (pip > 0 ? pip : 0) : 0;
        s_start = start;
    }
    __syncthreads();
    int start = s_start, len = s_len, nb = nbatch[b];
    if (threadIdx.x < LL) {
        int l = threadIdx.x;
        int idx = start + l;
        float v = (l < len && idx < nb) ? 1.f : 0.f;
        s_mk[l] = v;
        maskout[n*LL + l] = v;
    }
    __syncthreads();
    for (int e = threadIdx.x; e < LL*PNT; e += blockDim.x) {
        int l = e >> 5, d = e & 31;
        float mv = s_mk[l];
        int idx = start + l;
        if (idx < 0) idx = 0;
        if (idx > LMAXX-1) idx = LMAXX-1;
        float val;
        if (d < INDIM) {
            val = (mv > 0.f) ? data[(b*LMAXX + idx)*INDIM + d] : 0.f;
        } else {
            float tsm = (mv > 0.f) ? ts[b*LMAXX + idx] : 0.f;
            if (d == INDIM) val = tsm * teW[0] + teB[0];
            else { int j = d - INDIM - 1; val = sinf(tsm * tePW[j] + tePB[j]); }
        }
        xint[n*(LL*PNT) + e] = val;
    }
}

// ---------------------------------------------------------------- filter-gen MLP first two layers -> h2 (bf16 out)
__global__ void h2_kernel(const float* __restrict__ xint,
                          const float* __restrict__ W1, const float* __restrict__ b1,
                          const float* __restrict__ W2, const float* __restrict__ b2,
                          unsigned short* __restrict__ h2o)
{
    int n = blockIdx.x;
    __shared__ alignas(16) float Xs[LL*36];
    __shared__ alignas(16) float H1[LL*128];
    int tid = threadIdx.x;
    for (int f = tid; f < LL*8; f += blockDim.x) {
        int l = f >> 3, d4 = (f & 7)*4;
        *(float4*)&Xs[l*36 + d4] = *(const float4*)&xint[n*1024 + l*32 + d4];
    }
    __syncthreads();
    int j = tid;  // 0..127
    float acc[LL];
    if (j < TTCNN) {
        #pragma unroll
        for (int l = 0; l < LL; ++l) acc[l] = b1[j];
        for (int d4 = 0; d4 < 8; ++d4) {
            float w0 = W1[(d4*4+0)*TTCNN + j];
            float w1 = W1[(d4*4+1)*TTCNN + j];
            float w2 = W1[(d4*4+2)*TTCNN + j];
            float w3 = W1[(d4*4+3)*TTCNN + j];
            #pragma unroll
            for (int l = 0; l < LL; ++l) {
                float4 x = *(float4*)&Xs[l*36 + d4*4];
                acc[l] = fmaf(x.x, w0, acc[l]);
                acc[l] = fmaf(x.y, w1, acc[l]);
                acc[l] = fmaf(x.z, w2, acc[l]);
                acc[l] = fmaf(x.w, w3, acc[l]);
            }
        }
        #pragma unroll
        for (int l = 0; l < LL; ++l) H1[l*128 + j] = fmaxf(acc[l], 0.f);
    } else {
        #pragma unroll
        for (int l = 0; l < LL; ++l) H1[l*128 + 127] = 0.f;
    }
    __syncthreads();
    if (j < TTCNN) {
        #pragma unroll
        for (int l = 0; l < LL; ++l) acc[l] = b2[j];
        for (int k4 = 0; k4 < 32; ++k4) {
            int k = k4*4;
            float w0 = W2[(k+0)*TTCNN + j];
            float w1 = W2[(k+1)*TTCNN + j];
            float w2 = W2[(k+2)*TTCNN + j];
            float w3 = (k+3 < TTCNN) ? W2[(k+3)*TTCNN + j] : 0.f;
            #pragma unroll
            for (int l = 0; l < LL; ++l) {
                float4 h = *(float4*)&H1[l*128 + k];
                acc[l] = fmaf(h.x, w0, acc[l]);
                acc[l] = fmaf(h.y, w1, acc[l]);
                acc[l] = fmaf(h.z, w2, acc[l]);
                acc[l] = fmaf(h.w, w3, acc[l]);
            }
        }
        #pragma unroll
        for (int l = 0; l < LL; ++l) h2o[(n*LL + l)*128 + j] = f2bf(fmaxf(acc[l], 0.f));
    } else {
        #pragma unroll
        for (int l = 0; l < LL; ++l) h2o[(n*LL + l)*128 + 127] = 0;
    }
}

// ---------------------------------------------------------------- MFMA Filt GEMM + softmax + TTCN contraction
// grid: 4096 = 512 patches x 8 column-chunks (512 cols each, padded N=4096).
// block: 256 thr = 4 waves; wave handles 128 cols = 4 t-values.
__global__ __launch_bounds__(256) void ttcn_mfma_kernel(
    const unsigned short* __restrict__ h2b,   // [512][32][128] bf16
    const float* __restrict__ xint,           // [512][32][32]
    const float* __restrict__ mask,           // [512][32]
    const unsigned short* __restrict__ w3tb,  // [4096][128] bf16
    const float* __restrict__ b3,             // [4064]
    const float* __restrict__ tbias,          // [127]
    float* __restrict__ x)                    // [512][128]
{
    int bid = blockIdx.x;
    int n = bid >> 3, chunk = bid & 7;
    __shared__ alignas(16) unsigned short h2s[32*136];  // padded stride 136 bf16
    __shared__ alignas(16) float Xs[32*36];
    __shared__ float mk[32];
    int tid = threadIdx.x;
    for (int f = tid; f < 512; f += 256) {              // 32x128 bf16 tile
        int l = f >> 4, c16 = f & 15;
        *(short8v*)&h2s[l*136 + c16*8] = *(const short8v*)&h2b[(n*32 + l)*128 + c16*8];
    }
    {
        int l = tid >> 3, d4 = (tid & 7)*4;
        *(float4*)&Xs[l*36 + d4] = *(const float4*)&xint[n*1024 + l*32 + d4];
    }
    if (tid < 32) mk[tid] = mask[n*32 + tid];
    __syncthreads();
    if (chunk == 0 && tid == 0) {
        float e = 0.f;
        for (int l = 0; l < 32; ++l) e += mk[l];
        x[n*HIDD + 127] = (e > 0.f) ? 1.f : 0.f;
    }
    int wave = tid >> 6, lane = tid & 63;
    int li = lane & 15, hi = lane >> 4;
    // A fragments in registers: a[mt][kk]  (row = mt*16+li, k-slot = hi*8 + i)
    short8v a[2][4];
    #pragma unroll
    for (int mt = 0; mt < 2; ++mt)
        #pragma unroll
        for (int kk = 0; kk < 4; ++kk)
            a[mt][kk] = *(short8v*)&h2s[(mt*16 + li)*136 + kk*32 + hi*8];
    int cwbase = chunk*512 + wave*128;
    for (int tl = 0; tl < 4; ++tl) {
        int c0 = cwbase + tl*32;
        float4v acc[2][2] = {};   // [mt][nt2]
        #pragma unroll
        for (int nt2 = 0; nt2 < 2; ++nt2) {
            const unsigned short* bp = &w3tb[(size_t)(c0 + nt2*16 + li)*128 + hi*8];
            #pragma unroll
            for (int kk = 0; kk < 4; ++kk) {
                short8v bf = *(const short8v*)&bp[kk*32];
                acc[0][nt2] = __builtin_amdgcn_mfma_f32_16x16x32_bf16(a[0][kk], bf, acc[0][nt2], 0, 0, 0);
                acc[1][nt2] = __builtin_amdgcn_mfma_f32_16x16x32_bf16(a[1][kk], bf, acc[1][nt2], 0, 0, 0);
            }
        }
        // epilogue: per-column softmax over 32 rows + X-weighted sum, then t-reduce
        int t = c0 >> 5;
        float colv2 = 0.f;
        #pragma unroll
        for (int nt2 = 0; nt2 < 2; ++nt2) {
            int c = c0 + nt2*16 + li;
            float bv = (c < 4064) ? b3[c] : 0.f;
            int p = (nt2 << 4) + li;          // c & 31
            float fm[8];
            #pragma unroll
            for (int mt = 0; mt < 2; ++mt)
                #pragma unroll
                for (int r4 = 0; r4 < 4; ++r4) {
                    int r = mt*16 + hi*4 + r4;
                    float mv = mk[r];
                    fm[mt*4 + r4] = (acc[mt][nt2][r4] + bv)*mv + (1.f - mv)*(-1e8f);
                }
            float m = fm[0];
            #pragma unroll
            for (int i = 1; i < 8; ++i) m = fmaxf(m, fm[i]);
            m = fmaxf(m, __shfl_xor(m, 16));
            m = fmaxf(m, __shfl_xor(m, 32));
            float s = 0.f, w = 0.f;
            #pragma unroll
            for (int mt = 0; mt < 2; ++mt)
                #pragma unroll
                for (int r4 = 0; r4 < 4; ++r4) {
                    int r = mt*16 + hi*4 + r4;
                    float e = expf(fm[mt*4 + r4] - m);
                    s += e;
                    w += e * Xs[r*36 + p];
                }
            s += __shfl_xor(s, 16); w += __shfl_xor(w, 16);
            s += __shfl_xor(s, 32); w += __shfl_xor(w, 32);
            colv2 += w / s;
        }
        colv2 += __shfl_xor(colv2, 1);
        colv2 += __shfl_xor(colv2, 2);
        colv2 += __shfl_xor(colv2, 4);
        colv2 += __shfl_xor(colv2, 8);
        if (lane == 0 && t < TTCNN)
            x[n*HIDD + t] = fmaxf(colv2 + tbias[t], 0.f);
    }
}

// ---------------------------------------------------------------- generic fused linear (N multiple of 128)
__global__ __launch_bounds__(256) void lin_kernel(
    const float* __restrict__ A, int lda,
    const float* __restrict__ W0, const float* __restrict__ Wb0,
    const float* __restrict__ W1, const float* __restrict__ Wb1,
    const float* __restrict__ W2, const float* __restrict__ Wb2,
    float* __restrict__ O0, float* __restrict__ O1, float* __restrict__ O2,
    int M, int K, int N, int epi,
    const float* __restrict__ xres, const float* __restrict__ xlast_in,
    float* __restrict__ xlast_out,
    const float* __restrict__ pmk, const float* __restrict__ pe,
    const float* __restrict__ g, const float* __restrict__ bt)
{
    __shared__ alignas(16) float As[8*68];
    __shared__ float red[4][4][2];
    int tid = threadIdx.x;
    int cloc = tid & 127, rh = tid >> 7;
    int c = blockIdx.z*128 + cloc;
    int r0 = blockIdx.x*8;
    const float* W; const float* Wb; float* O;
    if (blockIdx.y == 0)      { W = W0; Wb = Wb0; O = O0; }
    else if (blockIdx.y == 1) { W = W1; Wb = Wb1; O = O1; }
    else                      { W = W2; Wb = Wb2; O = O2; }
    float acc0 = 0.f, acc1 = 0.f, acc2 = 0.f, acc3 = 0.f;
    for (int kc = 0; kc < K; kc += 64) {
        __syncthreads();
        if (tid < 128) {
            int row = tid >> 4, kk = (tid & 15)*4;
            int r = r0 + row;
            float4 v = make_float4(0.f, 0.f, 0.f, 0.f);
            if (r < M) v = *(const float4*)&A[(size_t)r*lda + kc + kk];
            *(float4*)&As[row*68 + kk] = v;
        }
        __syncthreads();
        const float* wp = &W[(size_t)kc*N + c];
        #pragma unroll 4
        for (int kk4 = 0; kk4 < 16; ++kk4) {
            float w0 = wp[(size_t)(kk4*4+0)*N];
            float w1 = wp[(size_t)(kk4*4+1)*N];
            float w2 = wp[(size_t)(kk4*4+2)*N];
            float w3 = wp[(size_t)(kk4*4+3)*N];
            float4 a0 = *(float4*)&As[(rh*4+0)*68 + kk4*4];
            float4 a1 = *(float4*)&As[(rh*4+1)*68 + kk4*4];
            float4 a2 = *(float4*)&As[(rh*4+2)*68 + kk4*4];
            float4 a3 = *(float4*)&As[(rh*4+3)*68 + kk4*4];
            acc0 += a0.x*w0 + a0.y*w1 + a0.z*w2 + a0.w*w3;
            acc1 += a1.x*w0 + a1.y*w1 + a1.z*w2 + a1.w*w3;
            acc2 += a2.x*w0 + a2.y*w1 + a2.z*w2 + a2.w*w3;
            acc3 += a3.x*w0 + a3.y*w1 + a3.z*w2 + a3.w*w3;
        }
    }
    float bv = Wb ? Wb[c] : 0.f;
    float val[4] = {acc0 + bv, acc1 + bv, acc2 + bv, acc3 + bv};
    int rbase = r0 + rh*4;
    if (epi == EPI_NONE || epi == EPI_RELU) {
        #pragma unroll
        for (int i = 0; i < 4; ++i) {
            int r = rbase + i;
            if (r < M) {
                float v = val[i];
                if (epi == EPI_RELU) v = fmaxf(v, 0.f);
                O[(size_t)r*N + c] = v;
            }
        }
    } else if (epi == EPI_GA) {
        #pragma unroll
        for (int i = 0; i < 4; ++i) {
            int r = rbase + i;
            float xr = xres[r*128 + cloc];
            float pmv = pmk[r];
            float pev = pe[(r & 63)*128 + cloc];
            xlast_out[r*128 + cloc] = xr;
            O[r*128 + cloc] = xr + val[i]*pmv + pev;
        }
    } else {
        float tv[4], s[4], s2[4];
        #pragma unroll
        for (int i = 0; i < 4; ++i) {
            int r = rbase + i;
            tv[i] = xres[r*128 + cloc] + val[i];
            s[i] = tv[i];
            s2[i] = tv[i]*tv[i];
        }
        #pragma unroll
        for (int i = 0; i < 4; ++i) {
            for (int off = 32; off >= 1; off >>= 1) {
                s[i]  += __shfl_xor(s[i],  off);
                s2[i] += __shfl_xor(s2[i], off);
            }
        }
        int wid = tid >> 6;
        if ((tid & 63) == 0) {
            #pragma unroll
            for (int i = 0; i < 4; ++i) { red[wid][i][0] = s[i]; red[wid][i][1] = s2[i]; }
        }
        __syncthreads();
        int pw = wid ^ 1;
        #pragma unroll
        for (int i = 0; i < 4; ++i) {
            float st  = red[wid][i][0] + red[pw][i][0];
            float s2t = red[wid][i][1] + red[pw][i][1];
            float mean = st * (1.f/128.f);
            float var = s2t * (1.f/128.f) - mean*mean;
            float rs = rsqrtf(var + 1e-5f);
            float y = (tv[i] - mean)*rs*g[cloc] + bt[cloc];
            int r = rbase + i;
            if (epi == EPI_LN) O[r*128 + cloc] = y;
            else               O[r*128 + cloc] = (xlast_in[r*128 + cloc] + y)*pmk[r];
        }
    }
}

// ---------------------------------------------------------------- 64-token MHA (4 heads, dh=32)
__global__ __launch_bounds__(256) void attn_kernel(
    const float* __restrict__ q, const float* __restrict__ k, const float* __restrict__ v,
    float* __restrict__ out, const float* __restrict__ tb,
    const float* __restrict__ pmk, int flags)
{
    int b = blockIdx.x >> 2, h = blockIdx.x & 3;
    __shared__ alignas(16) float qs[64*36];
    __shared__ alignas(16) float ks[64*36];
    __shared__ alignas(16) float vs[64*36];
    __shared__ float as_[64*68];
    int tid = threadIdx.x;
    for (int f = tid; f < 512; f += 256) {
        int m = f >> 3, d4 = (f & 7)*4;
        int gofs = (b*64 + m)*128 + h*32 + d4;
        *(float4*)&qs[m*36 + d4] = *(const float4*)&q[gofs];
        *(float4*)&ks[m*36 + d4] = *(const float4*)&k[gofs];
        *(float4*)&vs[m*36 + d4] = *(const float4*)&v[gofs];
    }
    __syncthreads();
    int r = tid >> 2, qd = tid & 3;
    float sreg[16];
    #pragma unroll
    for (int j = 0; j < 16; ++j) {
        int cc = qd*16 + j;
        float acc = 0.f;
        #pragma unroll
        for (int d4 = 0; d4 < 8; ++d4) {
            float4 a = *(float4*)&qs[r*36 + d4*4];
            float4 bb = *(float4*)&ks[cc*36 + d4*4];
            acc += a.x*bb.x + a.y*bb.y + a.z*bb.z + a.w*bb.w;
        }
        float s = acc * 0.17677669529663687f;
        if (flags & 1) s += tb[r*64 + cc];
        if (flags & 2) { if (pmk[b*64 + cc] <= 0.f) s = -1e9f; }
        sreg[j] = s;
    }
    float m = sreg[0];
    #pragma unroll
    for (int j = 1; j < 16; ++j) m = fmaxf(m, sreg[j]);
    m = fmaxf(m, __shfl_xor(m, 1));
    m = fmaxf(m, __shfl_xor(m, 2));
    float ssum = 0.f;
    #pragma unroll
    for (int j = 0; j < 16; ++j) { sreg[j] = expf(sreg[j] - m); ssum += sreg[j]; }
    ssum += __shfl_xor(ssum, 1);
    ssum += __shfl_xor(ssum, 2);
    float inv = 1.f / ssum;
    #pragma unroll
    for (int j = 0; j < 16; ++j) as_[r*68 + qd*16 + j] = sreg[j]*inv;
    __syncthreads();
    float o[8] = {0,0,0,0,0,0,0,0};
    for (int cc = 0; cc < 64; ++cc) {
        float a = as_[r*68 + cc];
        float4 v0 = *(float4*)&vs[cc*36 + qd*8];
        float4 v1 = *(float4*)&vs[cc*36 + qd*8 + 4];
        o[0] += a*v0.x; o[1] += a*v0.y; o[2] += a*v0.z; o[3] += a*v0.w;
        o[4] += a*v1.x; o[5] += a*v1.y; o[6] += a*v1.z; o[7] += a*v1.w;
    }
    int gobase = (b*64 + r)*128 + h*32 + qd*8;
    *(float4*)&out[gobase]   = make_float4(o[0], o[1], o[2], o[3]);
    *(float4*)&out[gobase+4] = make_float4(o[4], o[5], o[6], o[7]);
}

// ---------------------------------------------------------------- Weff = cls_Wo @ cls_out_W ; beff
__global__ void weff_kernel(const float* __restrict__ Wo, const float* __restrict__ bo,
                            const float* __restrict__ Wout, const float* __restrict__ bout,
                            float* __restrict__ weff)
{
    int d = threadIdx.x;
    float s = 0.f;
    for (int cc = 0; cc < 128; ++cc) s += Wo[d*128 + cc]*Wout[cc];
    weff[d] = s;
    if (d == 0) {
        float t = bout[0];
        for (int cc = 0; cc < 128; ++cc) t += bo[cc]*Wout[cc];
        weff[128] = t;
    }
}

// ---------------------------------------------------------------- cls attention + final logits
__global__ __launch_bounds__(256) void cls_attn_kernel(
    const float* __restrict__ qc, const float* __restrict__ k, const float* __restrict__ v,
    const float* __restrict__ pmk, const float* __restrict__ weff,
    float* __restrict__ outp)
{
    int b = blockIdx.x;
    __shared__ alignas(16) float ks[64*132];
    __shared__ alignas(16) float vs[64*132];
    __shared__ alignas(16) float q5[5*132];
    __shared__ float sb[5*68];
    __shared__ float z[5*132];
    int tid = threadIdx.x;
    for (int f = tid; f < 64*32; f += 256) {
        int m = f >> 5, d4 = (f & 31)*4;
        *(float4*)&ks[m*132 + d4] = *(const float4*)&k[(b*64+m)*128 + d4];
        *(float4*)&vs[m*132 + d4] = *(const float4*)&v[(b*64+m)*128 + d4];
    }
    for (int e = tid; e < 5*128; e += 256) {
        q5[(e >> 7)*132 + (e & 127)] = qc[e];
        z[(e >> 7)*132 + (e & 127)] = 0.f;
    }
    __syncthreads();
    for (int h = 0; h < 4; ++h) {
        for (int it = tid; it < 5*64; it += 256) {
            int qr = it >> 6, cc = it & 63;
            float acc = 0.f;
            #pragma unroll
            for (int d4 = 0; d4 < 8; ++d4) {
                float4 a = *(float4*)&q5[qr*132 + h*32 + d4*4];
                float4 bb = *(float4*)&ks[cc*132 + h*32 + d4*4];
                acc += a.x*bb.x + a.y*bb.y + a.z*bb.z + a.w*bb.w;
            }
            float s = acc * 0.17677669529663687f;
            if (pmk[b*64 + cc] <= 0.f) s = -1e9f;
            sb[qr*68 + cc] = s;
        }
        __syncthreads();
        if (tid < 5) {
            float m = -3e38f;
            for (int cc = 0; cc < 64; ++cc) m = fmaxf(m, sb[tid*68 + cc]);
            float ssum = 0.f;
            for (int cc = 0; cc < 64; ++cc) {
                float e = expf(sb[tid*68 + cc] - m);
                sb[tid*68 + cc] = e;
                ssum += e;
            }
            float inv = 1.f/ssum;
            for (int cc = 0; cc < 64; ++cc) sb[tid*68 + cc] *= inv;
        }
        __syncthreads();
        for (int it = tid; it < 5*32; it += 256) {
            int qr = it >> 5, d = it & 31;
            float acc = 0.f;
            for (int cc = 0; cc < 64; ++cc) acc += sb[qr*68 + cc]*vs[cc*132 + h*32 + d];
            z[qr*132 + h*32 + d] = acc;
        }
        __syncthreads();
    }
    if (tid < 5) {
        float acc = weff[128];
        for (int d = 0; d < 128; ++d) acc += z[tid*132 + d]*weff[d];
        outp[b*5 + tid] = acc;
    }
}

// ================================================================ launch
extern "C" void kernel_launch(void* const* d_in, const int* in_sizes, int n_in,
                              void* d_out, int out_size, void* d_ws, size_t ws_size,
                              hipStream_t stream)
{
    (void)n_in; (void)out_size; (void)ws_size;
    #define FP(i) ((const float*)d_in[i])
    const float* data = FP(0);
    const float* ts   = FP(1);
    const float* pmask= FP(2);
    const int*   pidx = (const int*)d_in[3];
    const int*   nb   = (const int*)d_in[4];
    const float* teW  = FP(5);
    const float* teB  = FP(6);
    const float* tePW = FP(7);
    const float* tePB = FP(8);
    const float* fgW1 = FP(9);
    const float* fgb1 = FP(10);
    const float* fgW2 = FP(11);
    const float* fgb2 = FP(12);
    const float* fgW3 = FP(13);
    const float* fgb3 = FP(14);
    const float* Tb   = FP(15);
    const float *gaWq,*gaWk,*gaWv,*gaWo,*tfWq,*tfWk,*tfWv,*tfWo;
    const float *gabq,*gabk,*gabv,*gabo,*tfbq,*tfbk,*tfbv,*tfbo,*ffb2;
    const float *ln1g,*ln1b,*ln2g,*ln2b,*ffW1,*ffb1,*ffW2;
    const float *clsq,*clsWq,*clsWk,*clsWv,*clsWo,*clsbq,*clsbk,*clsbv,*clsbo,*cloW,*clob;
    if (in_sizes[17] == 2*128*128) {  // setup_inputs dict order
        gaWq=FP(16); gaWk=FP(17); gaWv=FP(18); gaWo=FP(19);
        tfWq=FP(20); tfWk=FP(21); tfWv=FP(22); tfWo=FP(23);
        gabq=FP(24); gabk=FP(25); gabv=FP(26); gabo=FP(27);
        tfbq=FP(28); tfbk=FP(29); tfbv=FP(30); tfbo=FP(31);
        ffb2=FP(32); ln1g=FP(33); ln1b=FP(34); ln2g=FP(35); ln2b=FP(36);
        ffW1=FP(37); ffb1=FP(38); ffW2=FP(39);
        clsq=FP(40); clsWq=FP(41); clsWk=FP(42); clsWv=FP(43); clsWo=FP(44);
        clsbq=FP(45); clsbk=FP(46); clsbv=FP(47); clsbo=FP(48); cloW=FP(49); clob=FP(50);
    } else {                          // reference() signature order
        gaWq=FP(16); gabq=FP(17); gaWk=FP(18); gabk=FP(19);
        gaWv=FP(20); gabv=FP(21); gaWo=FP(22); gabo=FP(23);
        tfWq=FP(24); tfbq=FP(25); tfWk=FP(26); tfbk=FP(27);
        tfWv=FP(28); tfbv=FP(29); tfWo=FP(30); tfbo=FP(31);
        ln1g=FP(32); ln1b=FP(33); ffW1=FP(34); ffb1=FP(35); ffW2=FP(36); ffb2=FP(37);
        ln2g=FP(38); ln2b=FP(39);
        clsq=FP(40); clsWq=FP(41); clsbq=FP(42); clsWk=FP(43); clsbk=FP(44);
        clsWv=FP(45); clsbv=FP(46); clsWo=FP(47); clsbo=FP(48); cloW=FP(49); clob=FP(50);
    }

    float* ws   = (float*)d_ws;
    float* XINT = ws;                     // 524288 floats
    float* MASK = ws + 524288;            // 16384
    unsigned short* W3TB = (unsigned short*)(ws + 540672);   // 4096*128 bf16 = 1MB (slot is 2MB)
    unsigned short* H2Bb = (unsigned short*)(ws + 1060864);  // 512*32*128 bf16 = 4MB (slot is 8MB)
    float* X    = ws + 3158016;           // 65536
    float* XLAST= X + 65536;
    float* Q    = XLAST + 65536;
    float* Kb   = Q + 65536;
    float* Vb   = Kb + 65536;
    float* ATT  = Vb + 65536;
    float* HIDB = ATT + 65536;            // 1048576
    float* TBT  = HIDB + 1048576;         // 4096
    float* PET  = TBT + 4096;             // 8192
    float* WEFF = PET + 8192;             // 256
    float* QC5  = WEFF + 256;             // 640

    tables_kernel<<<48, 256, 0, stream>>>(TBT, PET);
    w3t_kernel<<<2048, 256, 0, stream>>>(fgW3, W3TB);
    prep_kernel<<<512, 128, 0, stream>>>(data, ts, pmask, pidx, nb, teW, teB, tePW, tePB, XINT, MASK);
    h2_kernel<<<512, 128, 0, stream>>>(XINT, fgW1, fgb1, fgW2, fgb2, H2Bb);
    ttcn_mfma_kernel<<<4096, 256, 0, stream>>>(H2Bb, XINT, MASK, W3TB, fgb3, Tb, X);

    for (int l = 0; l < 2; ++l) {
        const float* Wq = gaWq + l*16384; const float* bq = gabq + l*128;
        const float* Wk = gaWk + l*16384; const float* bk = gabk + l*128;
        const float* Wv = gaWv + l*16384; const float* bv = gabv + l*128;
        const float* Wo = gaWo + l*16384; const float* bo = gabo + l*128;
        // ga qkv
        lin_kernel<<<dim3(64,3,1), 256, 0, stream>>>(X, 128, Wq,bq, Wk,bk, Wv,bv, Q,Kb,Vb,
            512,128,128, EPI_NONE, nullptr,nullptr,nullptr,nullptr,nullptr,nullptr,nullptr);
        attn_kernel<<<32, 256, 0, stream>>>(Q, Kb, Vb, ATT, TBT, pmask, 3);
        // ga out-proj: x = x + ga*pm + pe ; save x_last
        lin_kernel<<<dim3(64,1,1), 256, 0, stream>>>(ATT, 128, Wo,bo, Wo,bo, Wo,bo, X,X,X,
            512,128,128, EPI_GA, X, nullptr, XLAST, pmask, PET, nullptr, nullptr);
        // tf qkv
        const float* Wq2 = tfWq + l*16384; const float* bq2 = tfbq + l*128;
        const float* Wk2 = tfWk + l*16384; const float* bk2 = tfbk + l*128;
        const float* Wv2 = tfWv + l*16384; const float* bv2 = tfbv + l*128;
        const float* Wo2 = tfWo + l*16384; const float* bo2 = tfbo + l*128;
        lin_kernel<<<dim3(64,3,1), 256, 0, stream>>>(X, 128, Wq2,bq2, Wk2,bk2, Wv2,bv2, Q,Kb,Vb,
            512,128,128, EPI_NONE, nullptr,nullptr,nullptr,nullptr,nullptr,nullptr,nullptr);
        attn_kernel<<<32, 256, 0, stream>>>(Q, Kb, Vb, ATT, TBT, pmask, 0);
        // tf out-proj + LN1(x + a)
        lin_kernel<<<dim3(64,1,1), 256, 0, stream>>>(ATT, 128, Wo2,bo2, Wo2,bo2, Wo2,bo2, X,X,X,
            512,128,128, EPI_LN, X, nullptr, nullptr, nullptr, nullptr, ln1g + l*128, ln1b + l*128);
        // FF1 relu
        lin_kernel<<<dim3(64,1,16), 256, 0, stream>>>(X, 128,
            ffW1 + (size_t)l*128*2048, ffb1 + l*2048, ffW1, ffb1, ffW1, ffb1, HIDB,HIDB,HIDB,
            512,128,2048, EPI_RELU, nullptr,nullptr,nullptr,nullptr,nullptr,nullptr,nullptr);
        // FF2 + LN2(x+f) + final residual*pm
        lin_kernel<<<dim3(64,1,1), 256, 0, stream>>>(HIDB, 2048,
            ffW2 + (size_t)l*2048*128, ffb2 + l*128, ffW2, ffb2, ffW2, ffb2, X,X,X,
            512,2048,128, EPI_LNF, X, XLAST, nullptr, pmask, nullptr, ln2g + l*128, ln2b + l*128);
    }

    // cls head
    lin_kernel<<<dim3(1,1,1), 256, 0, stream>>>(clsq, 128, clsWq,clsbq, clsWq,clsbq, clsWq,clsbq,
        QC5,QC5,QC5, 5,128,128, EPI_NONE, nullptr,nullptr,nullptr,nullptr,nullptr,nullptr,nullptr);
    lin_kernel<<<dim3(64,2,1), 256, 0, stream>>>(X, 128, clsWk,clsbk, clsWv,clsbv, clsWv,clsbv,
        Kb,Vb,Vb, 512,128,128, EPI_NONE, nullptr,nullptr,nullptr,nullptr,nullptr,nullptr,nullptr);
    weff_kernel<<<1, 128, 0, stream>>>(clsWo, clsbo, cloW, clob, WEFF);
    cls_attn_kernel<<<8, 256, 0, stream>>>(QC5, Kb, Vb, pmask, WEFF, (float*)d_out);
}

// Round 6
// 458.626 us; speedup vs baseline: 3.1825x; 1.2995x over previous
//
#include <hip/hip_runtime.h>
#include <math.h>

#define BB 8
#define PP 64
#define LL 32
#define LMAXX 2048
#define INDIM 12
#define PNT 32
#define HIDD 128
#define TTCNN 127
#define NPATCH 512

#define EPI_NONE 0
#define EPI_RELU 1
#define EPI_GA   2
#define EPI_LN   3
#define EPI_LNF  4

typedef __attribute__((ext_vector_type(8))) short short8v;
typedef __attribute__((ext_vector_type(4))) float float4v;

__device__ inline unsigned short f2bf(float f) {
    unsigned int u = __float_as_uint(f);
    unsigned int r = (u + 0x7FFFu + ((u >> 16) & 1u)) >> 16;
    return (unsigned short)r;
}

// ---------------------------------------------------------------- tables
__global__ void tables_kernel(float* __restrict__ tb, float* __restrict__ pe)
{
    int e = blockIdx.x*256 + threadIdx.x;
    if (e < 64*64) {
        int i = e >> 6, j = e & 63;
        float dist = fabsf((float)(i - j)) * (300.0f / 300.0f); // DELTA/TAU
        tb[e] = logf(expf(-dist) + 1e-12f);
    } else if (e < 64*64 + 64*128) {
        int e2 = e - 64*64;
        int i = e2 >> 7, d = e2 & 127;
        int mm = d >> 1;
        float div = expf((float)(2*mm) * (-logf(10000.f)/128.f));
        float ang = (float)i * div;
        pe[e2] = (d & 1) ? cosf(ang) : sinf(ang);
    }
}

// ---------------------------------------------------------------- W3 transpose -> bf16 [4096 cols][128 k], zero-padded
__global__ void w3t_kernel(const float* __restrict__ W3, unsigned short* __restrict__ W3TB)
{
    int e = blockIdx.x*256 + threadIdx.x;   // 4096*128 total
    if (e >= 4096*128) return;
    int kk = e >> 12, cidx = e & 4095;
    float v = (kk < TTCNN && cidx < 4064) ? W3[kk*4064 + cidx] : 0.f;
    W3TB[cidx*128 + kk] = f2bf(v);
}

// ---------------------------------------------------------------- gather + time-encode + filter-gen MLP (fused)
__global__ void prep_h2_kernel(const float* __restrict__ data, const float* __restrict__ ts,
                               const float* __restrict__ pmask, const int* __restrict__ pindex,
                               const int* __restrict__ nbatch,
                               const float* __restrict__ teW, const float* __restrict__ teB,
                               const float* __restrict__ tePW, const float* __restrict__ tePB,
                               const float* __restrict__ W1, const float* __restrict__ b1,
                               const float* __restrict__ W2, const float* __restrict__ b2,
                               float* __restrict__ xint, float* __restrict__ maskout,
                               unsigned short* __restrict__ h2o)
{
    int n = blockIdx.x;
    int b = n >> 6, p = n & 63;
    __shared__ int s_start, s_len;
    __shared__ float s_mk[LL];
    __shared__ alignas(16) float Xs[LL*36];
    __shared__ alignas(16) float H1[LL*128];
    int tid = threadIdx.x;
    if (tid == 0) {
        int start = 0;
        for (int j = 0; j < p; ++j) {
            float mv = pmask[b*PP + j];
            int pi = pindex[b*PP + j];
            start += (mv > 0.f) ? (pi > 0 ? pi : 0) : 0;
        }
        float mvp = pmask[b*PP + p];
        int pip = pindex[b*PP + p];
        s_len = (mvp > 0.f) ? (pip > 0 ? pip : 0) : 0;
        s_start = start;
    }
    __syncthreads();
    int start = s_start, len = s_len, nb2 = nbatch[b];
    if (tid < LL) {
        int l = tid;
        int idx = start + l;
        float v = (l < len && idx < nb2) ? 1.f : 0.f;
        s_mk[l] = v;
        maskout[n*LL + l] = v;
    }
    __syncthreads();
    for (int e = tid; e < LL*PNT; e += 128) {
        int l = e >> 5, d = e & 31;
        float mv = s_mk[l];
        int idx = start + l;
        if (idx < 0) idx = 0;
        if (idx > LMAXX-1) idx = LMAXX-1;
        float val;
        if (d < INDIM) {
            val = (mv > 0.f) ? data[(b*LMAXX + idx)*INDIM + d] : 0.f;
        } else {
            float tsm = (mv > 0.f) ? ts[b*LMAXX + idx] : 0.f;
            if (d == INDIM) val = tsm * teW[0] + teB[0];
            else { int j = d - INDIM - 1; val = sinf(tsm * tePW[j] + tePB[j]); }
        }
        Xs[l*36 + d] = val;
        xint[n*(LL*PNT) + e] = val;
    }
    __syncthreads();
    // ---- MLP layer 1+2 (each thread = one output column j)
    int j = tid;  // 0..127
    float acc[LL];
    if (j < TTCNN) {
        #pragma unroll
        for (int l = 0; l < LL; ++l) acc[l] = b1[j];
        for (int d4 = 0; d4 < 8; ++d4) {
            float w0 = W1[(d4*4+0)*TTCNN + j];
            float w1 = W1[(d4*4+1)*TTCNN + j];
            float w2 = W1[(d4*4+2)*TTCNN + j];
            float w3 = W1[(d4*4+3)*TTCNN + j];
            #pragma unroll
            for (int l = 0; l < LL; ++l) {
                float4 x = *(float4*)&Xs[l*36 + d4*4];
                acc[l] = fmaf(x.x, w0, acc[l]);
                acc[l] = fmaf(x.y, w1, acc[l]);
                acc[l] = fmaf(x.z, w2, acc[l]);
                acc[l] = fmaf(x.w, w3, acc[l]);
            }
        }
        #pragma unroll
        for (int l = 0; l < LL; ++l) H1[l*128 + j] = fmaxf(acc[l], 0.f);
    } else {
        #pragma unroll
        for (int l = 0; l < LL; ++l) H1[l*128 + 127] = 0.f;
    }
    __syncthreads();
    if (j < TTCNN) {
        #pragma unroll
        for (int l = 0; l < LL; ++l) acc[l] = b2[j];
        for (int k4 = 0; k4 < 32; ++k4) {
            int k = k4*4;
            float w0 = W2[(k+0)*TTCNN + j];
            float w1 = W2[(k+1)*TTCNN + j];
            float w2 = W2[(k+2)*TTCNN + j];
            float w3 = (k+3 < TTCNN) ? W2[(k+3)*TTCNN + j] : 0.f;
            #pragma unroll
            for (int l = 0; l < LL; ++l) {
                float4 h = *(float4*)&H1[l*128 + k];
                acc[l] = fmaf(h.x, w0, acc[l]);
                acc[l] = fmaf(h.y, w1, acc[l]);
                acc[l] = fmaf(h.z, w2, acc[l]);
                acc[l] = fmaf(h.w, w3, acc[l]);
            }
        }
        #pragma unroll
        for (int l = 0; l < LL; ++l) h2o[(n*LL + l)*128 + j] = f2bf(fmaxf(acc[l], 0.f));
    } else {
        #pragma unroll
        for (int l = 0; l < LL; ++l) h2o[(n*LL + l)*128 + 127] = 0;
    }
}

// ---------------------------------------------------------------- MFMA Filt GEMM + softmax + TTCN contraction
__global__ __launch_bounds__(256) void ttcn_mfma_kernel(
    const unsigned short* __restrict__ h2b,   // [512][32][128] bf16
    const float* __restrict__ xint,           // [512][32][32]
    const float* __restrict__ mask,           // [512][32]
    const unsigned short* __restrict__ w3tb,  // [4096][128] bf16
    const float* __restrict__ b3,             // [4064]
    const float* __restrict__ tbias,          // [127]
    float* __restrict__ x)                    // [512][128]
{
    int bid = blockIdx.x;
    int n = bid >> 3, chunk = bid & 7;
    __shared__ alignas(16) unsigned short h2s[32*136];
    __shared__ alignas(16) float Xs[32*36];
    __shared__ float mk[32];
    int tid = threadIdx.x;
    for (int f = tid; f < 512; f += 256) {
        int l = f >> 4, c16 = f & 15;
        *(short8v*)&h2s[l*136 + c16*8] = *(const short8v*)&h2b[(n*32 + l)*128 + c16*8];
    }
    {
        int l = tid >> 3, d4 = (tid & 7)*4;
        *(float4*)&Xs[l*36 + d4] = *(const float4*)&xint[n*1024 + l*32 + d4];
    }
    if (tid < 32) mk[tid] = mask[n*32 + tid];
    __syncthreads();
    if (chunk == 0 && tid == 0) {
        float e = 0.f;
        for (int l = 0; l < 32; ++l) e += mk[l];
        x[n*HIDD + 127] = (e > 0.f) ? 1.f : 0.f;
    }
    int wave = tid >> 6, lane = tid & 63;
    int li = lane & 15, hi = lane >> 4;
    short8v a[2][4];
    #pragma unroll
    for (int mt = 0; mt < 2; ++mt)
        #pragma unroll
        for (int kk = 0; kk < 4; ++kk)
            a[mt][kk] = *(short8v*)&h2s[(mt*16 + li)*136 + kk*32 + hi*8];
    int cwbase = chunk*512 + wave*128;
    for (int tl = 0; tl < 4; ++tl) {
        int c0 = cwbase + tl*32;
        float4v acc[2][2] = {};
        #pragma unroll
        for (int nt2 = 0; nt2 < 2; ++nt2) {
            const unsigned short* bp = &w3tb[(size_t)(c0 + nt2*16 + li)*128 + hi*8];
            #pragma unroll
            for (int kk = 0; kk < 4; ++kk) {
                short8v bf = *(const short8v*)&bp[kk*32];
                acc[0][nt2] = __builtin_amdgcn_mfma_f32_16x16x32_bf16(a[0][kk], bf, acc[0][nt2], 0, 0, 0);
                acc[1][nt2] = __builtin_amdgcn_mfma_f32_16x16x32_bf16(a[1][kk], bf, acc[1][nt2], 0, 0, 0);
            }
        }
        int t = c0 >> 5;
        float colv2 = 0.f;
        #pragma unroll
        for (int nt2 = 0; nt2 < 2; ++nt2) {
            int c = c0 + nt2*16 + li;
            float bv = (c < 4064) ? b3[c] : 0.f;
            int p = (nt2 << 4) + li;
            float fm[8];
            #pragma unroll
            for (int mt = 0; mt < 2; ++mt)
                #pragma unroll
                for (int r4 = 0; r4 < 4; ++r4) {
                    int r = mt*16 + hi*4 + r4;
                    float mv = mk[r];
                    fm[mt*4 + r4] = (acc[mt][nt2][r4] + bv)*mv + (1.f - mv)*(-1e8f);
                }
            float m = fm[0];
            #pragma unroll
            for (int i = 1; i < 8; ++i) m = fmaxf(m, fm[i]);
            m = fmaxf(m, __shfl_xor(m, 16));
            m = fmaxf(m, __shfl_xor(m, 32));
            float s = 0.f, w = 0.f;
            #pragma unroll
            for (int mt = 0; mt < 2; ++mt)
                #pragma unroll
                for (int r4 = 0; r4 < 4; ++r4) {
                    int r = mt*16 + hi*4 + r4;
                    float e = expf(fm[mt*4 + r4] - m);
                    s += e;
                    w += e * Xs[r*36 + p];
                }
            s += __shfl_xor(s, 16); w += __shfl_xor(w, 16);
            s += __shfl_xor(s, 32); w += __shfl_xor(w, 32);
            colv2 += w / s;
        }
        colv2 += __shfl_xor(colv2, 1);
        colv2 += __shfl_xor(colv2, 2);
        colv2 += __shfl_xor(colv2, 4);
        colv2 += __shfl_xor(colv2, 8);
        if (lane == 0 && t < TTCNN)
            x[n*HIDD + t] = fmaxf(colv2 + tbias[t], 0.f);
    }
}

// ---------------------------------------------------------------- generic fused linear (N multiple of 128)
__global__ __launch_bounds__(256) void lin_kernel(
    const float* __restrict__ A, int lda,
    const float* __restrict__ W0, const float* __restrict__ Wb0,
    const float* __restrict__ W1, const float* __restrict__ Wb1,
    const float* __restrict__ W2, const float* __restrict__ Wb2,
    float* __restrict__ O0, float* __restrict__ O1, float* __restrict__ O2,
    int M, int K, int N, int epi,
    const float* __restrict__ xres, const float* __restrict__ xlast_in,
    float* __restrict__ xlast_out,
    const float* __restrict__ pmk, const float* __restrict__ pe,
    const float* __restrict__ g, const float* __restrict__ bt)
{
    __shared__ alignas(16) float As[8*68];
    __shared__ float red[4][4][2];
    int tid = threadIdx.x;
    int cloc = tid & 127, rh = tid >> 7;
    int c = blockIdx.z*128 + cloc;
    int r0 = blockIdx.x*8;
    const float* W; const float* Wb; float* O;
    if (blockIdx.y == 0)      { W = W0; Wb = Wb0; O = O0; }
    else if (blockIdx.y == 1) { W = W1; Wb = Wb1; O = O1; }
    else                      { W = W2; Wb = Wb2; O = O2; }
    float acc0 = 0.f, acc1 = 0.f, acc2 = 0.f, acc3 = 0.f;
    for (int kc = 0; kc < K; kc += 64) {
        __syncthreads();
        if (tid < 128) {
            int row = tid >> 4, kk = (tid & 15)*4;
            int r = r0 + row;
            float4 v = make_float4(0.f, 0.f, 0.f, 0.f);
            if (r < M) v = *(const float4*)&A[(size_t)r*lda + kc + kk];
            *(float4*)&As[row*68 + kk] = v;
        }
        __syncthreads();
        const float* wp = &W[(size_t)kc*N + c];
        #pragma unroll 4
        for (int kk4 = 0; kk4 < 16; ++kk4) {
            float w0 = wp[(size_t)(kk4*4+0)*N];
            float w1 = wp[(size_t)(kk4*4+1)*N];
            float w2 = wp[(size_t)(kk4*4+2)*N];
            float w3 = wp[(size_t)(kk4*4+3)*N];
            float4 a0 = *(float4*)&As[(rh*4+0)*68 + kk4*4];
            float4 a1 = *(float4*)&As[(rh*4+1)*68 + kk4*4];
            float4 a2 = *(float4*)&As[(rh*4+2)*68 + kk4*4];
            float4 a3 = *(float4*)&As[(rh*4+3)*68 + kk4*4];
            acc0 += a0.x*w0 + a0.y*w1 + a0.z*w2 + a0.w*w3;
            acc1 += a1.x*w0 + a1.y*w1 + a1.z*w2 + a1.w*w3;
            acc2 += a2.x*w0 + a2.y*w1 + a2.z*w2 + a2.w*w3;
            acc3 += a3.x*w0 + a3.y*w1 + a3.z*w2 + a3.w*w3;
        }
    }
    float bv = Wb ? Wb[c] : 0.f;
    float val[4] = {acc0 + bv, acc1 + bv, acc2 + bv, acc3 + bv};
    int rbase = r0 + rh*4;
    if (epi == EPI_NONE || epi == EPI_RELU) {
        #pragma unroll
        for (int i = 0; i < 4; ++i) {
            int r = rbase + i;
            if (r < M) {
                float v = val[i];
                if (epi == EPI_RELU) v = fmaxf(v, 0.f);
                O[(size_t)r*N + c] = v;
            }
        }
    } else if (epi == EPI_GA) {
        #pragma unroll
        for (int i = 0; i < 4; ++i) {
            int r = rbase + i;
            float xr = xres[r*128 + cloc];
            float pmv = pmk[r];
            float pev = pe[(r & 63)*128 + cloc];
            xlast_out[r*128 + cloc] = xr;
            O[r*128 + cloc] = xr + val[i]*pmv + pev;
        }
    } else {
        float tv[4], s[4], s2[4];
        #pragma unroll
        for (int i = 0; i < 4; ++i) {
            int r = rbase + i;
            tv[i] = xres[r*128 + cloc] + val[i];
            s[i] = tv[i];
            s2[i] = tv[i]*tv[i];
        }
        #pragma unroll
        for (int i = 0; i < 4; ++i) {
            for (int off = 32; off >= 1; off >>= 1) {
                s[i]  += __shfl_xor(s[i],  off);
                s2[i] += __shfl_xor(s2[i], off);
            }
        }
        int wid = tid >> 6;
        if ((tid & 63) == 0) {
            #pragma unroll
            for (int i = 0; i < 4; ++i) { red[wid][i][0] = s[i]; red[wid][i][1] = s2[i]; }
        }
        __syncthreads();
        int pw = wid ^ 1;
        #pragma unroll
        for (int i = 0; i < 4; ++i) {
            float st  = red[wid][i][0] + red[pw][i][0];
            float s2t = red[wid][i][1] + red[pw][i][1];
            float mean = st * (1.f/128.f);
            float var = s2t * (1.f/128.f) - mean*mean;
            float rs = rsqrtf(var + 1e-5f);
            float y = (tv[i] - mean)*rs*g[cloc] + bt[cloc];
            int r = rbase + i;
            if (epi == EPI_LN) O[r*128 + cloc] = y;
            else               O[r*128 + cloc] = (xlast_in[r*128 + cloc] + y)*pmk[r];
        }
    }
}

// ---------------------------------------------------------------- FF2 split-K partials (K=2048 -> 8 x 256)
__global__ __launch_bounds__(256) void ff2_partial_kernel(
    const float* __restrict__ A,   // [512][2048]
    const float* __restrict__ W,   // [2048][128]
    float* __restrict__ PART)      // [8][512][128]
{
    __shared__ alignas(16) float As[8*68];
    int tid = threadIdx.x;
    int cloc = tid & 127, rh = tid >> 7;
    int r0 = blockIdx.x*8;
    int kz = blockIdx.z*256;
    float acc0 = 0.f, acc1 = 0.f, acc2 = 0.f, acc3 = 0.f;
    for (int kc = kz; kc < kz + 256; kc += 64) {
        __syncthreads();
        if (tid < 128) {
            int row = tid >> 4, kk = (tid & 15)*4;
            *(float4*)&As[row*68 + kk] = *(const float4*)&A[(size_t)(r0+row)*2048 + kc + kk];
        }
        __syncthreads();
        const float* wp = &W[(size_t)kc*128 + cloc];
        #pragma unroll 4
        for (int kk4 = 0; kk4 < 16; ++kk4) {
            float w0 = wp[(size_t)(kk4*4+0)*128];
            float w1 = wp[(size_t)(kk4*4+1)*128];
            float w2 = wp[(size_t)(kk4*4+2)*128];
            float w3 = wp[(size_t)(kk4*4+3)*128];
            float4 a0 = *(float4*)&As[(rh*4+0)*68 + kk4*4];
            float4 a1 = *(float4*)&As[(rh*4+1)*68 + kk4*4];
            float4 a2 = *(float4*)&As[(rh*4+2)*68 + kk4*4];
            float4 a3 = *(float4*)&As[(rh*4+3)*68 + kk4*4];
            acc0 += a0.x*w0 + a0.y*w1 + a0.z*w2 + a0.w*w3;
            acc1 += a1.x*w0 + a1.y*w1 + a1.z*w2 + a1.w*w3;
            acc2 += a2.x*w0 + a2.y*w1 + a2.z*w2 + a2.w*w3;
            acc3 += a3.x*w0 + a3.y*w1 + a3.z*w2 + a3.w*w3;
        }
    }
    float* pb = &PART[((size_t)blockIdx.z*512 + r0 + rh*4)*128 + cloc];
    pb[0]     = acc0;
    pb[128]   = acc1;
    pb[256]   = acc2;
    pb[384]   = acc3;
}

// ---------------------------------------------------------------- FF2 epilogue: sum partials + bias + LN2 + final residual
__global__ void ln2f_kernel(const float* __restrict__ PART, const float* __restrict__ b2,
                            const float* __restrict__ xres, const float* __restrict__ xlast,
                            const float* __restrict__ pmk,
                            const float* __restrict__ g, const float* __restrict__ bt,
                            float* __restrict__ xout)
{
    int r = blockIdx.x, c = threadIdx.x;  // 512 blocks x 128 threads
    float v = b2[c];
    #pragma unroll
    for (int z = 0; z < 8; ++z) v += PART[((size_t)z*512 + r)*128 + c];
    float tv = xres[r*128 + c] + v;
    float s = tv, s2 = tv*tv;
    for (int off = 32; off >= 1; off >>= 1) {
        s  += __shfl_xor(s,  off);
        s2 += __shfl_xor(s2, off);
    }
    __shared__ float red[2][2];
    int w = c >> 6;
    if ((c & 63) == 0) { red[w][0] = s; red[w][1] = s2; }
    __syncthreads();
    float st  = red[0][0] + red[1][0];
    float s2t = red[0][1] + red[1][1];
    float mean = st * (1.f/128.f);
    float var = s2t * (1.f/128.f) - mean*mean;
    float y = (tv - mean)*rsqrtf(var + 1e-5f)*g[c] + bt[c];
    xout[r*128 + c] = (xlast[r*128 + c] + y)*pmk[r];
}

// ---------------------------------------------------------------- 64-token MHA (4 heads, dh=32), split q-rows x2
__global__ __launch_bounds__(256) void attn_kernel(
    const float* __restrict__ q, const float* __restrict__ k, const float* __restrict__ v,
    float* __restrict__ out, const float* __restrict__ tb,
    const float* __restrict__ pmk, int flags)
{
    int bid = blockIdx.x;                       // 64 = 8b x 4h x 2half
    int b = bid >> 3, h = (bid >> 1) & 3, half = bid & 1;
    int rbase = half*32;
    __shared__ alignas(16) float qs[32*36];
    __shared__ alignas(16) float ks[64*36];
    __shared__ alignas(16) float vs[64*36];
    __shared__ float as_[32*68];
    int tid = threadIdx.x;
    {
        int m = tid >> 3, d4 = (tid & 7)*4;     // 256 = 32 rows x 8 float4
        *(float4*)&qs[m*36 + d4] = *(const float4*)&q[(b*64 + rbase + m)*128 + h*32 + d4];
    }
    for (int f = tid; f < 512; f += 256) {
        int m = f >> 3, d4 = (f & 7)*4;
        int gofs = (b*64 + m)*128 + h*32 + d4;
        *(float4*)&ks[m*36 + d4] = *(const float4*)&k[gofs];
        *(float4*)&vs[m*36 + d4] = *(const float4*)&v[gofs];
    }
    __syncthreads();
    int r = tid >> 3, qd = tid & 7;             // r 0..31 local, 8 threads/row
    float sreg[8];
    #pragma unroll
    for (int j = 0; j < 8; ++j) {
        int cc = j*8 + qd;                      // distinct start banks across qd
        float acc = 0.f;
        #pragma unroll
        for (int d4 = 0; d4 < 8; ++d4) {
            float4 a = *(float4*)&qs[r*36 + d4*4];
            float4 bb = *(float4*)&ks[cc*36 + d4*4];
            acc += a.x*bb.x + a.y*bb.y + a.z*bb.z + a.w*bb.w;
        }
        float s = acc * 0.17677669529663687f;
        if (flags & 1) s += tb[(rbase + r)*64 + cc];
        if (flags & 2) { if (pmk[b*64 + cc] <= 0.f) s = -1e9f; }
        sreg[j] = s;
    }
    float m = sreg[0];
    #pragma unroll
    for (int j = 1; j < 8; ++j) m = fmaxf(m, sreg[j]);
    m = fmaxf(m, __shfl_xor(m, 1));
    m = fmaxf(m, __shfl_xor(m, 2));
    m = fmaxf(m, __shfl_xor(m, 4));
    float ssum = 0.f;
    #pragma unroll
    for (int j = 0; j < 8; ++j) { sreg[j] = expf(sreg[j] - m); ssum += sreg[j]; }
    ssum += __shfl_xor(ssum, 1);
    ssum += __shfl_xor(ssum, 2);
    ssum += __shfl_xor(ssum, 4);
    float inv = 1.f / ssum;
    #pragma unroll
    for (int j = 0; j < 8; ++j) as_[r*68 + j*8 + qd] = sreg[j]*inv;
    __syncthreads();
    float o0 = 0.f, o1 = 0.f, o2 = 0.f, o3 = 0.f;
    int d0 = qd*4;
    for (int cc = 0; cc < 64; ++cc) {
        float a = as_[r*68 + cc];
        float4 v4 = *(float4*)&vs[cc*36 + d0];
        o0 += a*v4.x; o1 += a*v4.y; o2 += a*v4.z; o3 += a*v4.w;
    }
    *(float4*)&out[(b*64 + rbase + r)*128 + h*32 + d0] = make_float4(o0, o1, o2, o3);
}

// ---------------------------------------------------------------- cls: q-proj + attention + Weff logits (fused)
__global__ __launch_bounds__(256) void cls_attn_kernel(
    const float* __restrict__ clsq, const float* __restrict__ Wq, const float* __restrict__ bq,
    const float* __restrict__ k, const float* __restrict__ v,
    const float* __restrict__ pmk,
    const float* __restrict__ Wo, const float* __restrict__ bo,
    const float* __restrict__ WoutW, const float* __restrict__ boutB,
    float* __restrict__ outp)
{
    int b = blockIdx.x;
    __shared__ alignas(16) float ks[64*132];
    __shared__ alignas(16) float vs[64*132];
    __shared__ alignas(16) float q5[5*132];
    __shared__ float cq[5*128];
    __shared__ float sb[5*68];
    __shared__ float z[5*132];
    __shared__ float wef[129];
    int tid = threadIdx.x;
    for (int f = tid; f < 64*32; f += 256) {
        int m = f >> 5, d4 = (f & 31)*4;
        *(float4*)&ks[m*132 + d4] = *(const float4*)&k[(b*64+m)*128 + d4];
        *(float4*)&vs[m*132 + d4] = *(const float4*)&v[(b*64+m)*128 + d4];
    }
    for (int e = tid; e < 5*128; e += 256) {
        cq[e] = clsq[e];
        z[(e >> 7)*132 + (e & 127)] = 0.f;
    }
    __syncthreads();
    // q5 = clsq @ Wq + bq
    for (int it = tid; it < 5*128; it += 256) {
        int qr = it >> 7, d = it & 127;
        float a = bq[d];
        for (int kk = 0; kk < 128; ++kk) a += cq[qr*128 + kk]*Wq[kk*128 + d];
        q5[qr*132 + d] = a;
    }
    // weff = Wo @ WoutW ; beff
    if (tid < 128) {
        float s = 0.f;
        for (int cc = 0; cc < 128; ++cc) s += Wo[tid*128 + cc]*WoutW[cc];
        wef[tid] = s;
    } else if (tid == 128) {
        float t = boutB[0];
        for (int cc = 0; cc < 128; ++cc) t += bo[cc]*WoutW[cc];
        wef[128] = t;
    }
    __syncthreads();
    for (int h = 0; h < 4; ++h) {
        for (int it = tid; it < 5*64; it += 256) {
            int qr = it >> 6, cc = it & 63;
            float acc = 0.f;
            #pragma unroll
            for (int d4 = 0; d4 < 8; ++d4) {
                float4 a = *(float4*)&q5[qr*132 + h*32 + d4*4];
                float4 bb = *(float4*)&ks[cc*132 + h*32 + d4*4];
                acc += a.x*bb.x + a.y*bb.y + a.z*bb.z + a.w*bb.w;
            }
            float s = acc * 0.17677669529663687f;
            if (pmk[b*64 + cc] <= 0.f) s = -1e9f;
            sb[qr*68 + cc] = s;
        }
        __syncthreads();
        if (tid < 5) {
            float m = -3e38f;
            for (int cc = 0; cc < 64; ++cc) m = fmaxf(m, sb[tid*68 + cc]);
            float ssum = 0.f;
            for (int cc = 0; cc < 64; ++cc) {
                float e = expf(sb[tid*68 + cc] - m);
                sb[tid*68 + cc] = e;
                ssum += e;
            }
            float inv = 1.f/ssum;
            for (int cc = 0; cc < 64; ++cc) sb[tid*68 + cc] *= inv;
        }
        __syncthreads();
        for (int it = tid; it < 5*32; it += 256) {
            int qr = it >> 5, d = it & 31;
            float acc = 0.f;
            for (int cc = 0; cc < 64; ++cc) acc += sb[qr*68 + cc]*vs[cc*132 + h*32 + d];
            z[qr*132 + h*32 + d] = acc;
        }
        __syncthreads();
    }
    if (tid < 5) {
        float acc = wef[128];
        for (int d = 0; d < 128; ++d) acc += z[tid*132 + d]*wef[d];
        outp[b*5 + tid] = acc;
    }
}

// ================================================================ launch
extern "C" void kernel_launch(void* const* d_in, const int* in_sizes, int n_in,
                              void* d_out, int out_size, void* d_ws, size_t ws_size,
                              hipStream_t stream)
{
    (void)n_in; (void)out_size; (void)ws_size;
    #define FP(i) ((const float*)d_in[i])
    const float* data = FP(0);
    const float* ts   = FP(1);
    const float* pmask= FP(2);
    const int*   pidx = (const int*)d_in[3];
    const int*   nb   = (const int*)d_in[4];
    const float* teW  = FP(5);
    const float* teB  = FP(6);
    const float* tePW = FP(7);
    const float* tePB = FP(8);
    const float* fgW1 = FP(9);
    const float* fgb1 = FP(10);
    const float* fgW2 = FP(11);
    const float* fgb2 = FP(12);
    const float* fgW3 = FP(13);
    const float* fgb3 = FP(14);
    const float* Tb   = FP(15);
    const float *gaWq,*gaWk,*gaWv,*gaWo,*tfWq,*tfWk,*tfWv,*tfWo;
    const float *gabq,*gabk,*gabv,*gabo,*tfbq,*tfbk,*tfbv,*tfbo,*ffb2;
    const float *ln1g,*ln1b,*ln2g,*ln2b,*ffW1,*ffb1,*ffW2;
    const float *clsq,*clsWq,*clsWk,*clsWv,*clsWo,*clsbq,*clsbk,*clsbv,*clsbo,*cloW,*clob;
    if (in_sizes[17] == 2*128*128) {  // setup_inputs dict order
        gaWq=FP(16); gaWk=FP(17); gaWv=FP(18); gaWo=FP(19);
        tfWq=FP(20); tfWk=FP(21); tfWv=FP(22); tfWo=FP(23);
        gabq=FP(24); gabk=FP(25); gabv=FP(26); gabo=FP(27);
        tfbq=FP(28); tfbk=FP(29); tfbv=FP(30); tfbo=FP(31);
        ffb2=FP(32); ln1g=FP(33); ln1b=FP(34); ln2g=FP(35); ln2b=FP(36);
        ffW1=FP(37); ffb1=FP(38); ffW2=FP(39);
        clsq=FP(40); clsWq=FP(41); clsWk=FP(42); clsWv=FP(43); clsWo=FP(44);
        clsbq=FP(45); clsbk=FP(46); clsbv=FP(47); clsbo=FP(48); cloW=FP(49); clob=FP(50);
    } else {                          // reference() signature order
        gaWq=FP(16); gabq=FP(17); gaWk=FP(18); gabk=FP(19);
        gaWv=FP(20); gabv=FP(21); gaWo=FP(22); gabo=FP(23);
        tfWq=FP(24); tfbq=FP(25); tfWk=FP(26); tfbk=FP(27);
        tfWv=FP(28); tfbv=FP(29); tfWo=FP(30); tfbo=FP(31);
        ln1g=FP(32); ln1b=FP(33); ffW1=FP(34); ffb1=FP(35); ffW2=FP(36); ffb2=FP(37);
        ln2g=FP(38); ln2b=FP(39);
        clsq=FP(40); clsWq=FP(41); clsbq=FP(42); clsWk=FP(43); clsbk=FP(44);
        clsWv=FP(45); clsbv=FP(46); clsWo=FP(47); clsbo=FP(48); cloW=FP(49); clob=FP(50);
    }

    float* ws   = (float*)d_ws;
    float* XINT = ws;                     // 524288 floats (prelude only)
    float* PART = ws;                     // FF2 partials alias XINT (dead after ttcn)
    float* MASK = ws + 524288;            // 16384
    unsigned short* W3TB = (unsigned short*)(ws + 540672);   // 4096*128 bf16
    unsigned short* H2Bb = (unsigned short*)(ws + 1060864);  // 512*32*128 bf16
    float* X    = ws + 3158016;           // 65536
    float* XLAST= X + 65536;
    float* Q    = XLAST + 65536;
    float* Kb   = Q + 65536;
    float* Vb   = Kb + 65536;
    float* ATT  = Vb + 65536;
    float* HIDB = ATT + 65536;            // 1048576
    float* TBT  = HIDB + 1048576;         // 4096
    float* PET  = TBT + 4096;             // 8192

    tables_kernel<<<48, 256, 0, stream>>>(TBT, PET);
    w3t_kernel<<<2048, 256, 0, stream>>>(fgW3, W3TB);
    prep_h2_kernel<<<512, 128, 0, stream>>>(data, ts, pmask, pidx, nb, teW, teB, tePW, tePB,
                                            fgW1, fgb1, fgW2, fgb2, XINT, MASK, H2Bb);
    ttcn_mfma_kernel<<<4096, 256, 0, stream>>>(H2Bb, XINT, MASK, W3TB, fgb3, Tb, X);

    for (int l = 0; l < 2; ++l) {
        const float* Wq = gaWq + l*16384; const float* bq = gabq + l*128;
        const float* Wk = gaWk + l*16384; const float* bk = gabk + l*128;
        const float* Wv = gaWv + l*16384; const float* bv = gabv + l*128;
        const float* Wo = gaWo + l*16384; const float* bo = gabo + l*128;
        // ga qkv
        lin_kernel<<<dim3(64,3,1), 256, 0, stream>>>(X, 128, Wq,bq, Wk,bk, Wv,bv, Q,Kb,Vb,
            512,128,128, EPI_NONE, nullptr,nullptr,nullptr,nullptr,nullptr,nullptr,nullptr);
        attn_kernel<<<64, 256, 0, stream>>>(Q, Kb, Vb, ATT, TBT, pmask, 3);
        // ga out-proj: x = x + ga*pm + pe ; save x_last
        lin_kernel<<<dim3(64,1,1), 256, 0, stream>>>(ATT, 128, Wo,bo, Wo,bo, Wo,bo, X,X,X,
            512,128,128, EPI_GA, X, nullptr, XLAST, pmask, PET, nullptr, nullptr);
        // tf qkv
        const float* Wq2 = tfWq + l*16384; const float* bq2 = tfbq + l*128;
        const float* Wk2 = tfWk + l*16384; const float* bk2 = tfbk + l*128;
        const float* Wv2 = tfWv + l*16384; const float* bv2 = tfbv + l*128;
        const float* Wo2 = tfWo + l*16384; const float* bo2 = tfbo + l*128;
        lin_kernel<<<dim3(64,3,1), 256, 0, stream>>>(X, 128, Wq2,bq2, Wk2,bk2, Wv2,bv2, Q,Kb,Vb,
            512,128,128, EPI_NONE, nullptr,nullptr,nullptr,nullptr,nullptr,nullptr,nullptr);
        attn_kernel<<<64, 256, 0, stream>>>(Q, Kb, Vb, ATT, TBT, pmask, 0);
        // tf out-proj + LN1(x + a)
        lin_kernel<<<dim3(64,1,1), 256, 0, stream>>>(ATT, 128, Wo2,bo2, Wo2,bo2, Wo2,bo2, X,X,X,
            512,128,128, EPI_LN, X, nullptr, nullptr, nullptr, nullptr, ln1g + l*128, ln1b + l*128);
        // FF1 relu
        lin_kernel<<<dim3(64,1,16), 256, 0, stream>>>(X, 128,
            ffW1 + (size_t)l*128*2048, ffb1 + l*2048, ffW1, ffb1, ffW1, ffb1, HIDB,HIDB,HIDB,
            512,128,2048, EPI_RELU, nullptr,nullptr,nullptr,nullptr,nullptr,nullptr,nullptr);
        // FF2 split-K partials + LN2 epilogue
        ff2_partial_kernel<<<dim3(64,1,8), 256, 0, stream>>>(HIDB, ffW2 + (size_t)l*2048*128, PART);
        ln2f_kernel<<<512, 128, 0, stream>>>(PART, ffb2 + l*128, X, XLAST, pmask,
                                             ln2g + l*128, ln2b + l*128, X);
    }

    // cls head: K/V projection then fused q-proj + attention + logits
    lin_kernel<<<dim3(64,2,1), 256, 0, stream>>>(X, 128, clsWk,clsbk, clsWv,clsbv, clsWv,clsbv,
        Kb,Vb,Vb, 512,128,128, EPI_NONE, nullptr,nullptr,nullptr,nullptr,nullptr,nullptr,nullptr);
    cls_attn_kernel<<<8, 256, 0, stream>>>(clsq, clsWq, clsbq, Kb, Vb, pmask,
                                           clsWo, clsbo, cloW, clob, (float*)d_out);
}